// Round 3
// baseline (3001.074 us; speedup 1.0000x reference)
//
#include <hip/hip_runtime.h>
#include <math.h>

namespace {

constexpr int NN = 100000;
constexpr int NE = 1600000;
constexpr float EPS = 1e-5f;

__device__ __forceinline__ float leaky(float x) { return x > 0.f ? x : 0.01f * x; }

// ---------------- preprocessing: degrees, dinv, CSR-by-dst ----------------

__global__ __launch_bounds__(256) void k_init(int* __restrict__ deg, int* __restrict__ counter, int n) {
  int i = blockIdx.x * 256 + threadIdx.x;
  if (i < n) deg[i] = 1;          // self-loop
  if (i == 0) counter[0] = 0;
}

__global__ __launch_bounds__(256) void k_count(const int* __restrict__ dst, int* __restrict__ deg, int e) {
  int i = blockIdx.x * 256 + threadIdx.x;
  if (i < e) atomicAdd(&deg[dst[i]], 1);
}

// dinv = rsqrt(deg); allocate CSR slot ranges via wave-aggregated atomic
__global__ __launch_bounds__(256) void k_alloc(const int* __restrict__ deg, float* __restrict__ dinv,
                                               int* __restrict__ offsets, int* __restrict__ cursor,
                                               int* __restrict__ counter, int n) {
  int i = blockIdx.x * 256 + threadIdx.x;
  int lane = threadIdx.x & 63;
  int c = 0;
  if (i < n) {
    int d = deg[i];
    dinv[i] = rsqrtf((float)d);
    c = d - 1;                    // real in-edges only (self-loop handled analytically)
  }
  // wave inclusive scan
  int v = c;
#pragma unroll
  for (int s = 1; s < 64; s <<= 1) {
    int t = __shfl_up(v, s, 64);
    if (lane >= s) v += t;
  }
  int total = __shfl(v, 63, 64);
  int base = 0;
  if (lane == 63) base = atomicAdd(counter, total);
  base = __shfl(base, 63, 64);
  if (i < n) {
    int off = base + v - c;       // exclusive prefix
    offsets[i] = off;
    cursor[i] = off;
  }
}

__global__ __launch_bounds__(256) void k_fill(const int* __restrict__ src, const int* __restrict__ dst,
                                              const float* __restrict__ dinv, int* __restrict__ cursor,
                                              int* __restrict__ adj_src, float* __restrict__ adj_norm, int e) {
  int i = blockIdx.x * 256 + threadIdx.x;
  if (i < e) {
    int s = src[i], d = dst[i];
    int p = atomicAdd(&cursor[d], 1);
    adj_src[p] = s;
    adj_norm[p] = dinv[s] * dinv[d];
  }
}

// zero-pad gw1 [94][128] -> [96][128]
__global__ __launch_bounds__(256) void k_padw1(const float* __restrict__ gw1, float* __restrict__ w1p) {
  int i = blockIdx.x * 256 + threadIdx.x;
  if (i < 96 * 128) w1p[i] = (i < 94 * 128) ? gw1[i] : 0.f;
}

// ---------------- CNN encoder ----------------
// per node: in [1][100][5] -> conv(10,3x3)+leaky -> conv(20,3x2)+leaky -> conv(1,3x2) -> tanh
// -> H[94] (stride 96, cols 94,95 = 0)
// block = 256 threads = 2 nodes x 128 threads. conv3 fused (c2 stays in registers,
// partial sums via LDS part[]). LDS ~38 KB -> 4 blocks/CU = 16 waves/CU.
// NOTE: grid is exactly NN/2 full blocks (NN even) — no tail guards needed.
__global__ __launch_bounds__(256, 4) void k_cnn(const float* __restrict__ x,
                                             const float* __restrict__ cw1, const float* __restrict__ cb1,
                                             const float* __restrict__ cw2, const float* __restrict__ cb2,
                                             const float* __restrict__ cw3, const float* __restrict__ cb3,
                                             float* __restrict__ H) {
  __shared__ float w1s[90];
  __shared__ float b1s[10];
  __shared__ __align__(16) float w2s[1600];   // [co*10+ci]*8 + q  (q=kh*2+kw, pad 6..7)
  __shared__ float b2s[20];
  __shared__ __align__(16) float w3s[160];    // ci*8 + q (pad 6..7)
  __shared__ float b3sv[1];
  __shared__ __align__(16) float inb[2][500];
  __shared__ float c1[2][2940];               // [10 ci][98 h][3 w]
  __shared__ float part[2][4][98];            // conv3 partial sums per cog

  int tid = threadIdx.x;
  if (tid < 90) w1s[tid] = cw1[tid];
  if (tid < 10) b1s[tid] = cb1[tid];
  for (int i = tid; i < 1200; i += 256) w2s[(i / 6) * 8 + i % 6] = cw2[i];
  if (tid < 20) b2s[tid] = cb2[tid];
  if (tid < 120) w3s[(tid / 6) * 8 + tid % 6] = cw3[tid];
  if (tid == 0) b3sv[0] = cb3[0];
  for (int i = tid; i < 2 * 4 * 98; i += 256) ((float*)part)[i] = 0.f;

  int half = tid >> 7;          // which node in block
  int nt = tid & 127;           // thread id within node
  int node = blockIdx.x * 2 + half;

  if (nt < 125) {
    const float4* xp = (const float4*)(x + (size_t)node * 500);
    ((float4*)inb[half])[nt] = xp[nt];
  }
  __syncthreads();

  {
    // conv1: positions p=(h,w) over 98x3, all 10 co per thread
    const float* in = inb[half];
    float* c1p = c1[half];
    for (int p = nt; p < 294; p += 128) {
      int h = p / 3, w = p - h * 3;
      float xv[9];
#pragma unroll
      for (int kh = 0; kh < 3; kh++)
#pragma unroll
        for (int kw = 0; kw < 3; kw++) xv[kh * 3 + kw] = in[(h + kh) * 5 + w + kw];
#pragma unroll
      for (int co = 0; co < 10; co++) {
        float a = b1s[co];
#pragma unroll
        for (int q = 0; q < 9; q++) a += xv[q] * w1s[co * 9 + q];
        c1p[co * 294 + p] = leaky(a);
      }
    }
  }
  __syncthreads();

  // conv2: thread tile = 3h x 2w x 5co; 32 h-groups x 4 co-groups = 128 threads/node
  int hg = nt & 31, cog = nt >> 5;
  int h0 = hg * 3, co0 = cog * 5;
  float acc[3][2][5];
  {
    float* c1p = c1[half];
#pragma unroll
    for (int a = 0; a < 3; a++)
#pragma unroll
      for (int b = 0; b < 2; b++)
#pragma unroll
        for (int c = 0; c < 5; c++) acc[a][b][c] = 0.f;
#pragma unroll 1
    for (int ci = 0; ci < 10; ci++) {
      float r[5][3];
      const float* base = c1p + ci * 294 + h0 * 3;
#pragma unroll
      for (int i = 0; i < 5; i++)
#pragma unroll
        for (int j = 0; j < 3; j++) r[i][j] = base[i * 3 + j];
      float wt[5][6];
#pragma unroll
      for (int c = 0; c < 5; c++) {
        const float4 a4 = *(const float4*)&w2s[((co0 + c) * 10 + ci) * 8];
        const float2 a2 = *(const float2*)&w2s[((co0 + c) * 10 + ci) * 8 + 4];
        wt[c][0] = a4.x; wt[c][1] = a4.y; wt[c][2] = a4.z; wt[c][3] = a4.w;
        wt[c][4] = a2.x; wt[c][5] = a2.y;
      }
#pragma unroll
      for (int hh = 0; hh < 3; hh++)
#pragma unroll
        for (int w = 0; w < 2; w++)
#pragma unroll
          for (int c = 0; c < 5; c++)
            acc[hh][w][c] += r[hh][w] * wt[c][0] + r[hh][w + 1] * wt[c][1]
                           + r[hh + 1][w] * wt[c][2] + r[hh + 1][w + 1] * wt[c][3]
                           + r[hh + 2][w] * wt[c][4] + r[hh + 2][w + 1] * wt[c][5];
    }
    // bias + leaky -> acc now holds c2 values for rows h0..h0+2, co0..co0+4
#pragma unroll
    for (int hh = 0; hh < 3; hh++)
#pragma unroll
      for (int w = 0; w < 2; w++)
#pragma unroll
        for (int c = 0; c < 5; c++)
          acc[hh][w][c] = leaky(acc[hh][w][c] + b2s[co0 + c]);
  }
  __syncthreads();   // part[] zeroing (pre-conv1) and conv2 regs complete

  // conv3 fused: H[h] = b3 + sum_{ci,kh,kw} c2[ci][h+kh][kw]*w3[ci][kh*2+kw]
  // thread contributes its acc tile to part[half][cog][h+2], phased by kh so that
  // within a phase every LDS address is written by exactly one thread of the block.
  {
    float wt3[5][6];
#pragma unroll
    for (int c = 0; c < 5; c++) {
      const float4 a4 = *(const float4*)&w3s[(co0 + c) * 8];
      const float2 a2 = *(const float2*)&w3s[(co0 + c) * 8 + 4];
      wt3[c][0] = a4.x; wt3[c][1] = a4.y; wt3[c][2] = a4.z; wt3[c][3] = a4.w;
      wt3[c][4] = a2.x; wt3[c][5] = a2.y;
    }
    float* pp = &part[half][cog][0];
#pragma unroll
    for (int kh = 0; kh < 3; kh++) {
#pragma unroll
      for (int hh = 0; hh < 3; hh++) {
        float s = 0.f;
#pragma unroll
        for (int c = 0; c < 5; c++)
#pragma unroll
          for (int w = 0; w < 2; w++)
            s += acc[hh][w][c] * wt3[c][kh * 2 + w];
        pp[h0 + hh - kh + 2] += s;   // addresses distinct across block within this kh
      }
      __syncthreads();
    }
  }

  {
    float* Hp = H + (size_t)node * 96;
    if (nt < 94) {
      float v = part[half][0][nt + 2] + part[half][1][nt + 2]
              + part[half][2][nt + 2] + part[half][3][nt + 2] + b3sv[0];
      Hp[nt] = tanhf(v);
    } else if (nt < 96) {
      Hp[nt] = 0.f;
    }
  }
}

// ---------------- GEMM: C[M,FO-tile] = A[M,K] @ W[K,FO] ----------------
template <int K, int FO, int BN>
__global__ __launch_bounds__(256) void k_gemm(const float* __restrict__ A, const float* __restrict__ W,
                                              float* __restrict__ C, int M) {
  __shared__ float As[64][K + 1];
  __shared__ __align__(16) float Ws[K][BN];
  int tid = threadIdx.x;
  int row_base = blockIdx.x * 64;
  int col_base = blockIdx.y * BN;

  for (int idx = tid; idx < 64 * K; idx += 256) {
    int r = idx / K, k = idx - r * K;
    int row = row_base + r;
    As[r][k] = (row < M) ? A[(size_t)row * K + k] : 0.f;
  }
  for (int idx = tid; idx < K * BN; idx += 256) {
    int r = idx / BN, c = idx - r * BN;
    Ws[r][c] = W[r * FO + col_base + c];
  }
  __syncthreads();

  if constexpr (BN == 64) {
    int ty = tid >> 4, tx = tid & 15;
    float acc[4][4] = {};
#pragma unroll 4
    for (int k = 0; k < K; k++) {
      float a0 = As[ty * 4 + 0][k];
      float a1 = As[ty * 4 + 1][k];
      float a2 = As[ty * 4 + 2][k];
      float a3 = As[ty * 4 + 3][k];
      const float4 b = *(const float4*)&Ws[k][tx * 4];
      acc[0][0] += a0 * b.x; acc[0][1] += a0 * b.y; acc[0][2] += a0 * b.z; acc[0][3] += a0 * b.w;
      acc[1][0] += a1 * b.x; acc[1][1] += a1 * b.y; acc[1][2] += a1 * b.z; acc[1][3] += a1 * b.w;
      acc[2][0] += a2 * b.x; acc[2][1] += a2 * b.y; acc[2][2] += a2 * b.z; acc[2][3] += a2 * b.w;
      acc[3][0] += a3 * b.x; acc[3][1] += a3 * b.y; acc[3][2] += a3 * b.z; acc[3][3] += a3 * b.w;
    }
#pragma unroll
    for (int i = 0; i < 4; i++) {
      int row = row_base + ty * 4 + i;
      if (row < M) {
        float4 v = make_float4(acc[i][0], acc[i][1], acc[i][2], acc[i][3]);
        *(float4*)&C[(size_t)row * FO + col_base + tx * 4] = v;
      }
    }
  } else {  // BN == 16: thread = 1 row x 4 cols
    int ty = tid >> 2, tx = tid & 3;
    float acc[4] = {};
#pragma unroll 4
    for (int k = 0; k < K; k++) {
      float a = As[ty][k];
      const float4 b = *(const float4*)&Ws[k][tx * 4];
      acc[0] += a * b.x; acc[1] += a * b.y; acc[2] += a * b.z; acc[3] += a * b.w;
    }
    int row = row_base + ty;
    if (row < M) *(float4*)&C[(size_t)row * FO + col_base + tx * 4] = make_float4(acc[0], acc[1], acc[2], acc[3]);
  }
}

// ---------------- aggregation + bias + BN (+tanh | +softmax) ----------------
template <int FO, bool SOFT>
__global__ __launch_bounds__(256) void k_agg(const float* __restrict__ XW,
                                             const int* __restrict__ offsets, const int* __restrict__ deg,
                                             const int* __restrict__ adj_src, const float* __restrict__ adj_norm,
                                             const float* __restrict__ dinv,
                                             const float* __restrict__ gb, const float* __restrict__ bg,
                                             const float* __restrict__ bb, const float* __restrict__ bm,
                                             const float* __restrict__ bv,
                                             float* __restrict__ out, int n) {
  constexpr int NPB = 256 / FO;
  int tid = threadIdx.x;
  int li = tid / FO, col = tid % FO;
  int node = blockIdx.x * NPB + li;
  if (node >= n) return;

  float dv = dinv[node];
  float acc = XW[(size_t)node * FO + col] * dv * dv;  // self-loop
  int start = offsets[node];
  int cnt = deg[node] - 1;
  for (int e = 0; e < cnt; e++) {
    int s = adj_src[start + e];
    float nm = adj_norm[start + e];
    acc += XW[(size_t)s * FO + col] * nm;
  }
  float scale = bg[col] * rsqrtf(bv[col] + EPS);
  float v = (acc + gb[col] - bm[col]) * scale + bb[col];
  if constexpr (SOFT) {
    float mx = v;
#pragma unroll
    for (int m = 8; m; m >>= 1) mx = fmaxf(mx, __shfl_xor(mx, m, 16));
    float ex = expf(v - mx);
    float sm = ex;
#pragma unroll
    for (int m = 8; m; m >>= 1) sm += __shfl_xor(sm, m, 16);
    out[(size_t)node * FO + col] = ex / sm;
  } else {
    out[(size_t)node * FO + col] = tanhf(v);
  }
}

}  // namespace

extern "C" void kernel_launch(void* const* d_in, const int* in_sizes, int n_in,
                              void* d_out, int out_size, void* d_ws, size_t ws_size,
                              hipStream_t stream) {
  const float* x   = (const float*)d_in[0];
  const int*   ei  = (const int*)d_in[1];
  const float* cw1 = (const float*)d_in[2];
  const float* cb1 = (const float*)d_in[3];
  const float* cw2 = (const float*)d_in[4];
  const float* cb2 = (const float*)d_in[5];
  const float* cw3 = (const float*)d_in[6];
  const float* cb3 = (const float*)d_in[7];
  const float *gw[5], *gb[5], *bng[5], *bnb[5], *bnm[5], *bnv[5];
  for (int l = 0; l < 5; l++) {
    gw[l]  = (const float*)d_in[8 + 6 * l + 0];
    gb[l]  = (const float*)d_in[8 + 6 * l + 1];
    bng[l] = (const float*)d_in[8 + 6 * l + 2];
    bnb[l] = (const float*)d_in[8 + 6 * l + 3];
    bnm[l] = (const float*)d_in[8 + 6 * l + 4];
    bnv[l] = (const float*)d_in[8 + 6 * l + 5];
  }
  const int* srcp = ei;
  const int* dstp = ei + NE;

  char* w = (char*)d_ws;
  auto alloc = [&](size_t bytes) { char* p = w; w += (bytes + 255) & ~255ULL; return p; };
  int*   deg     = (int*)alloc((size_t)NN * 4);
  int*   offsets = (int*)alloc((size_t)NN * 4);
  int*   cursor  = (int*)alloc((size_t)NN * 4);
  int*   counter = (int*)alloc(256);
  float* dinv    = (float*)alloc((size_t)NN * 4);
  int*   adj_src = (int*)alloc((size_t)NE * 4);
  float* adj_nm  = (float*)alloc((size_t)NE * 4);
  float* w1p     = (float*)alloc(96 * 128 * 4);
  float* bufA    = (float*)alloc((size_t)NN * 128 * 4);
  float* bufB    = (float*)alloc((size_t)NN * 128 * 4);
  float* bufC    = (float*)alloc((size_t)NN * 128 * 4);

  int nb_n = (NN + 255) / 256;
  int nb_e = (NE + 255) / 256;
  k_init<<<nb_n, 256, 0, stream>>>(deg, counter, NN);
  k_count<<<nb_e, 256, 0, stream>>>(dstp, deg, NE);
  k_alloc<<<nb_n, 256, 0, stream>>>(deg, dinv, offsets, cursor, counter, NN);
  k_fill<<<nb_e, 256, 0, stream>>>(srcp, dstp, dinv, cursor, adj_src, adj_nm, NE);
  k_padw1<<<48, 256, 0, stream>>>(gw[0], w1p);

  k_cnn<<<NN / 2, 256, 0, stream>>>(x, cw1, cb1, cw2, cb2, cw3, cb3, bufA);

  int gx = (NN + 63) / 64;
  // L1: H[N,96] @ W1p[96,128] -> agg(FO=128) tanh
  k_gemm<96, 128, 64><<<dim3(gx, 2), 256, 0, stream>>>(bufA, w1p, bufB, NN);
  k_agg<128, false><<<(NN + 1) / 2, 256, 0, stream>>>(bufB, offsets, deg, adj_src, adj_nm, dinv,
                                                      gb[0], bng[0], bnb[0], bnm[0], bnv[0], bufC, NN);
  // L2: [N,128]@[128,128]
  k_gemm<128, 128, 64><<<dim3(gx, 2), 256, 0, stream>>>(bufC, gw[1], bufB, NN);
  k_agg<128, false><<<(NN + 1) / 2, 256, 0, stream>>>(bufB, offsets, deg, adj_src, adj_nm, dinv,
                                                      gb[1], bng[1], bnb[1], bnm[1], bnv[1], bufA, NN);
  // L3: [N,128]@[128,64]
  k_gemm<128, 64, 64><<<dim3(gx, 1), 256, 0, stream>>>(bufA, gw[2], bufB, NN);
  k_agg<64, false><<<(NN + 3) / 4, 256, 0, stream>>>(bufB, offsets, deg, adj_src, adj_nm, dinv,
                                                     gb[2], bng[2], bnb[2], bnm[2], bnv[2], bufC, NN);
  // L4: [N,64]@[64,64]
  k_gemm<64, 64, 64><<<dim3(gx, 1), 256, 0, stream>>>(bufC, gw[3], bufB, NN);
  k_agg<64, false><<<(NN + 3) / 4, 256, 0, stream>>>(bufB, offsets, deg, adj_src, adj_nm, dinv,
                                                     gb[3], bng[3], bnb[3], bnm[3], bnv[3], bufA, NN);
  // L5: [N,64]@[64,16] -> agg + BN + softmax -> d_out
  k_gemm<64, 16, 16><<<dim3(gx, 1), 256, 0, stream>>>(bufA, gw[4], bufB, NN);
  k_agg<16, true><<<(NN + 15) / 16, 256, 0, stream>>>(bufB, offsets, deg, adj_src, adj_nm, dinv,
                                                      gb[4], bng[4], bnb[4], bnm[4], bnv[4], (float*)d_out, NN);
}

// Round 4
// 2551.191 us; speedup vs baseline: 1.1763x; 1.1763x over previous
//
#include <hip/hip_runtime.h>
#include <math.h>

namespace {

constexpr int NN = 100000;
constexpr int NE = 1600000;
constexpr float EPS = 1e-5f;

__device__ __forceinline__ float leaky(float x) { return x > 0.f ? x : 0.01f * x; }

// ---------------- preprocessing: degrees, dinv, CSR-by-dst ----------------

__global__ __launch_bounds__(256) void k_init(int* __restrict__ deg, int* __restrict__ counter, int n) {
  int i = blockIdx.x * 256 + threadIdx.x;
  if (i < n) deg[i] = 1;          // self-loop
  if (i == 0) counter[0] = 0;
}

__global__ __launch_bounds__(256) void k_count(const int* __restrict__ dst, int* __restrict__ deg, int e) {
  int i = blockIdx.x * 256 + threadIdx.x;
  if (i < e) atomicAdd(&deg[dst[i]], 1);
}

// dinv = rsqrt(deg); allocate CSR slot ranges via wave-aggregated atomic
__global__ __launch_bounds__(256) void k_alloc(const int* __restrict__ deg, float* __restrict__ dinv,
                                               int* __restrict__ offsets, int* __restrict__ cursor,
                                               int* __restrict__ counter, int n) {
  int i = blockIdx.x * 256 + threadIdx.x;
  int lane = threadIdx.x & 63;
  int c = 0;
  if (i < n) {
    int d = deg[i];
    dinv[i] = rsqrtf((float)d);
    c = d - 1;                    // real in-edges only (self-loop handled analytically)
  }
  // wave inclusive scan
  int v = c;
#pragma unroll
  for (int s = 1; s < 64; s <<= 1) {
    int t = __shfl_up(v, s, 64);
    if (lane >= s) v += t;
  }
  int total = __shfl(v, 63, 64);
  int base = 0;
  if (lane == 63) base = atomicAdd(counter, total);
  base = __shfl(base, 63, 64);
  if (i < n) {
    int off = base + v - c;       // exclusive prefix
    offsets[i] = off;
    cursor[i] = off;
  }
}

__global__ __launch_bounds__(256) void k_fill(const int* __restrict__ src, const int* __restrict__ dst,
                                              const float* __restrict__ dinv, int* __restrict__ cursor,
                                              int* __restrict__ adj_src, float* __restrict__ adj_norm, int e) {
  int i = blockIdx.x * 256 + threadIdx.x;
  if (i < e) {
    int s = src[i], d = dst[i];
    int p = atomicAdd(&cursor[d], 1);
    adj_src[p] = s;
    adj_norm[p] = dinv[s] * dinv[d];
  }
}

// zero-pad gw1 [94][128] -> [96][128]
__global__ __launch_bounds__(256) void k_padw1(const float* __restrict__ gw1, float* __restrict__ w1p) {
  int i = blockIdx.x * 256 + threadIdx.x;
  if (i < 96 * 128) w1p[i] = (i < 94 * 128) ? gw1[i] : 0.f;
}

// ---------------- CNN encoder ----------------
// per node: in [1][100][5] -> conv(10,3x3)+leaky -> conv(20,3x2)+leaky -> conv(1,3x2) -> tanh
// -> H[94] (stride 96, cols 94,95 = 0)
// block = 256 threads = 2 nodes x 128 threads. conv3 fused (c2 stays in registers,
// partial sums via LDS part[]). LDS ~38 KB -> 4 blocks/CU; NO VGPR cap (R3 lesson:
// __launch_bounds__(256,4) forced 64 VGPR -> 4.7 GB scratch spill, 1.4x slower).
// Grid is exactly NN/2 full blocks (NN even) — no tail guards needed.
__global__ __launch_bounds__(256) void k_cnn(const float* __restrict__ x,
                                             const float* __restrict__ cw1, const float* __restrict__ cb1,
                                             const float* __restrict__ cw2, const float* __restrict__ cb2,
                                             const float* __restrict__ cw3, const float* __restrict__ cb3,
                                             float* __restrict__ H) {
  __shared__ float w1s[90];
  __shared__ float b1s[10];
  __shared__ __align__(16) float w2s[1600];   // [co*10+ci]*8 + q  (q=kh*2+kw, pad 6..7)
  __shared__ float b2s[20];
  __shared__ __align__(16) float w3s[160];    // ci*8 + q (pad 6..7)
  __shared__ float b3sv[1];
  __shared__ __align__(16) float inb[2][500];
  __shared__ float c1[2][2940];               // [10 ci][98 h][3 w]
  __shared__ float part[2][4][98];            // conv3 partial sums per cog

  int tid = threadIdx.x;
  if (tid < 90) w1s[tid] = cw1[tid];
  if (tid < 10) b1s[tid] = cb1[tid];
  for (int i = tid; i < 1200; i += 256) w2s[(i / 6) * 8 + i % 6] = cw2[i];
  if (tid < 20) b2s[tid] = cb2[tid];
  if (tid < 120) w3s[(tid / 6) * 8 + tid % 6] = cw3[tid];
  if (tid == 0) b3sv[0] = cb3[0];
  for (int i = tid; i < 2 * 4 * 98; i += 256) ((float*)part)[i] = 0.f;

  int half = tid >> 7;          // which node in block
  int nt = tid & 127;           // thread id within node
  int node = blockIdx.x * 2 + half;

  if (nt < 125) {
    const float4* xp = (const float4*)(x + (size_t)node * 500);
    ((float4*)inb[half])[nt] = xp[nt];
  }
  __syncthreads();

  {
    // conv1: positions p=(h,w) over 98x3, all 10 co per thread
    const float* in = inb[half];
    float* c1p = c1[half];
    for (int p = nt; p < 294; p += 128) {
      int h = p / 3, w = p - h * 3;
      float xv[9];
#pragma unroll
      for (int kh = 0; kh < 3; kh++)
#pragma unroll
        for (int kw = 0; kw < 3; kw++) xv[kh * 3 + kw] = in[(h + kh) * 5 + w + kw];
#pragma unroll
      for (int co = 0; co < 10; co++) {
        float a = b1s[co];
#pragma unroll
        for (int q = 0; q < 9; q++) a += xv[q] * w1s[co * 9 + q];
        c1p[co * 294 + p] = leaky(a);
      }
    }
  }
  __syncthreads();

  // conv2: thread tile = 3h x 2w x 5co; 32 h-groups x 4 co-groups = 128 threads/node
  int hg = nt & 31, cog = nt >> 5;
  int h0 = hg * 3, co0 = cog * 5;
  float acc[3][2][5];
  {
    float* c1p = c1[half];
#pragma unroll
    for (int a = 0; a < 3; a++)
#pragma unroll
      for (int b = 0; b < 2; b++)
#pragma unroll
        for (int c = 0; c < 5; c++) acc[a][b][c] = 0.f;
#pragma unroll 1
    for (int ci = 0; ci < 10; ci++) {
      float r[5][3];
      const float* base = c1p + ci * 294 + h0 * 3;
#pragma unroll
      for (int i = 0; i < 5; i++)
#pragma unroll
        for (int j = 0; j < 3; j++) r[i][j] = base[i * 3 + j];
#pragma unroll
      for (int c = 0; c < 5; c++) {
        const float4 a4 = *(const float4*)&w2s[((co0 + c) * 10 + ci) * 8];
        const float2 a2 = *(const float2*)&w2s[((co0 + c) * 10 + ci) * 8 + 4];
#pragma unroll
        for (int hh = 0; hh < 3; hh++)
#pragma unroll
          for (int w = 0; w < 2; w++)
            acc[hh][w][c] += r[hh][w] * a4.x + r[hh][w + 1] * a4.y
                           + r[hh + 1][w] * a4.z + r[hh + 1][w + 1] * a4.w
                           + r[hh + 2][w] * a2.x + r[hh + 2][w + 1] * a2.y;
      }
    }
    // bias + leaky -> acc now holds c2 values for rows h0..h0+2, co0..co0+4
#pragma unroll
    for (int hh = 0; hh < 3; hh++)
#pragma unroll
      for (int w = 0; w < 2; w++)
#pragma unroll
        for (int c = 0; c < 5; c++)
          acc[hh][w][c] = leaky(acc[hh][w][c] + b2s[co0 + c]);
  }
  __syncthreads();   // part[] zeroing and conv2 regs complete

  // conv3 fused: H[h] = b3 + sum_{ci,kh,kw} c2[ci][h+kh][kw]*w3[ci][kh*2+kw]
  // thread contributes its acc tile to part[half][cog][h+2], phased by kh so that
  // within a phase every LDS address is written by exactly one thread of the block.
  {
    float* pp = &part[half][cog][0];
#pragma unroll
    for (int kh = 0; kh < 3; kh++) {
#pragma unroll
      for (int hh = 0; hh < 3; hh++) {
        float s = 0.f;
#pragma unroll
        for (int c = 0; c < 5; c++) {
          const float2 w2v = *(const float2*)&w3s[(co0 + c) * 8 + kh * 2];
          s += acc[hh][0][c] * w2v.x + acc[hh][1][c] * w2v.y;
        }
        pp[h0 + hh - kh + 2] += s;   // addresses distinct across block within this kh
      }
      __syncthreads();
    }
  }

  {
    float* Hp = H + (size_t)node * 96;
    if (nt < 94) {
      float v = part[half][0][nt + 2] + part[half][1][nt + 2]
              + part[half][2][nt + 2] + part[half][3][nt + 2] + b3sv[0];
      Hp[nt] = tanhf(v);
    } else if (nt < 96) {
      Hp[nt] = 0.f;
    }
  }
}

// ---------------- GEMM: C[M,FO-tile] = A[M,K] @ W[K,FO] ----------------
template <int K, int FO, int BN>
__global__ __launch_bounds__(256) void k_gemm(const float* __restrict__ A, const float* __restrict__ W,
                                              float* __restrict__ C, int M) {
  __shared__ float As[64][K + 1];
  __shared__ __align__(16) float Ws[K][BN];
  int tid = threadIdx.x;
  int row_base = blockIdx.x * 64;
  int col_base = blockIdx.y * BN;

  for (int idx = tid; idx < 64 * K; idx += 256) {
    int r = idx / K, k = idx - r * K;
    int row = row_base + r;
    As[r][k] = (row < M) ? A[(size_t)row * K + k] : 0.f;
  }
  for (int idx = tid; idx < K * BN; idx += 256) {
    int r = idx / BN, c = idx - r * BN;
    Ws[r][c] = W[r * FO + col_base + c];
  }
  __syncthreads();

  if constexpr (BN == 64) {
    int ty = tid >> 4, tx = tid & 15;
    float acc[4][4] = {};
#pragma unroll 4
    for (int k = 0; k < K; k++) {
      float a0 = As[ty * 4 + 0][k];
      float a1 = As[ty * 4 + 1][k];
      float a2 = As[ty * 4 + 2][k];
      float a3 = As[ty * 4 + 3][k];
      const float4 b = *(const float4*)&Ws[k][tx * 4];
      acc[0][0] += a0 * b.x; acc[0][1] += a0 * b.y; acc[0][2] += a0 * b.z; acc[0][3] += a0 * b.w;
      acc[1][0] += a1 * b.x; acc[1][1] += a1 * b.y; acc[1][2] += a1 * b.z; acc[1][3] += a1 * b.w;
      acc[2][0] += a2 * b.x; acc[2][1] += a2 * b.y; acc[2][2] += a2 * b.z; acc[2][3] += a2 * b.w;
      acc[3][0] += a3 * b.x; acc[3][1] += a3 * b.y; acc[3][2] += a3 * b.z; acc[3][3] += a3 * b.w;
    }
#pragma unroll
    for (int i = 0; i < 4; i++) {
      int row = row_base + ty * 4 + i;
      if (row < M) {
        float4 v = make_float4(acc[i][0], acc[i][1], acc[i][2], acc[i][3]);
        *(float4*)&C[(size_t)row * FO + col_base + tx * 4] = v;
      }
    }
  } else {  // BN == 16: thread = 1 row x 4 cols
    int ty = tid >> 2, tx = tid & 3;
    float acc[4] = {};
#pragma unroll 4
    for (int k = 0; k < K; k++) {
      float a = As[ty][k];
      const float4 b = *(const float4*)&Ws[k][tx * 4];
      acc[0] += a * b.x; acc[1] += a * b.y; acc[2] += a * b.z; acc[3] += a * b.w;
    }
    int row = row_base + ty;
    if (row < M) *(float4*)&C[(size_t)row * FO + col_base + tx * 4] = make_float4(acc[0], acc[1], acc[2], acc[3]);
  }
}

// ---------------- aggregation + bias + BN (+tanh | +softmax) ----------------
template <int FO, bool SOFT>
__global__ __launch_bounds__(256) void k_agg(const float* __restrict__ XW,
                                             const int* __restrict__ offsets, const int* __restrict__ deg,
                                             const int* __restrict__ adj_src, const float* __restrict__ adj_norm,
                                             const float* __restrict__ dinv,
                                             const float* __restrict__ gb, const float* __restrict__ bg,
                                             const float* __restrict__ bb, const float* __restrict__ bm,
                                             const float* __restrict__ bv,
                                             float* __restrict__ out, int n) {
  constexpr int NPB = 256 / FO;
  int tid = threadIdx.x;
  int li = tid / FO, col = tid % FO;
  int node = blockIdx.x * NPB + li;
  if (node >= n) return;

  float dv = dinv[node];
  float acc = XW[(size_t)node * FO + col] * dv * dv;  // self-loop
  int start = offsets[node];
  int cnt = deg[node] - 1;
  for (int e = 0; e < cnt; e++) {
    int s = adj_src[start + e];
    float nm = adj_norm[start + e];
    acc += XW[(size_t)s * FO + col] * nm;
  }
  float scale = bg[col] * rsqrtf(bv[col] + EPS);
  float v = (acc + gb[col] - bm[col]) * scale + bb[col];
  if constexpr (SOFT) {
    float mx = v;
#pragma unroll
    for (int m = 8; m; m >>= 1) mx = fmaxf(mx, __shfl_xor(mx, m, 16));
    float ex = expf(v - mx);
    float sm = ex;
#pragma unroll
    for (int m = 8; m; m >>= 1) sm += __shfl_xor(sm, m, 16);
    out[(size_t)node * FO + col] = ex / sm;
  } else {
    out[(size_t)node * FO + col] = tanhf(v);
  }
}

}  // namespace

extern "C" void kernel_launch(void* const* d_in, const int* in_sizes, int n_in,
                              void* d_out, int out_size, void* d_ws, size_t ws_size,
                              hipStream_t stream) {
  const float* x   = (const float*)d_in[0];
  const int*   ei  = (const int*)d_in[1];
  const float* cw1 = (const float*)d_in[2];
  const float* cb1 = (const float*)d_in[3];
  const float* cw2 = (const float*)d_in[4];
  const float* cb2 = (const float*)d_in[5];
  const float* cw3 = (const float*)d_in[6];
  const float* cb3 = (const float*)d_in[7];
  const float *gw[5], *gb[5], *bng[5], *bnb[5], *bnm[5], *bnv[5];
  for (int l = 0; l < 5; l++) {
    gw[l]  = (const float*)d_in[8 + 6 * l + 0];
    gb[l]  = (const float*)d_in[8 + 6 * l + 1];
    bng[l] = (const float*)d_in[8 + 6 * l + 2];
    bnb[l] = (const float*)d_in[8 + 6 * l + 3];
    bnm[l] = (const float*)d_in[8 + 6 * l + 4];
    bnv[l] = (const float*)d_in[8 + 6 * l + 5];
  }
  const int* srcp = ei;
  const int* dstp = ei + NE;

  char* w = (char*)d_ws;
  auto alloc = [&](size_t bytes) { char* p = w; w += (bytes + 255) & ~255ULL; return p; };
  int*   deg     = (int*)alloc((size_t)NN * 4);
  int*   offsets = (int*)alloc((size_t)NN * 4);
  int*   cursor  = (int*)alloc((size_t)NN * 4);
  int*   counter = (int*)alloc(256);
  float* dinv    = (float*)alloc((size_t)NN * 4);
  int*   adj_src = (int*)alloc((size_t)NE * 4);
  float* adj_nm  = (float*)alloc((size_t)NE * 4);
  float* w1p     = (float*)alloc(96 * 128 * 4);
  float* bufA    = (float*)alloc((size_t)NN * 128 * 4);
  float* bufB    = (float*)alloc((size_t)NN * 128 * 4);
  float* bufC    = (float*)alloc((size_t)NN * 128 * 4);

  int nb_n = (NN + 255) / 256;
  int nb_e = (NE + 255) / 256;
  k_init<<<nb_n, 256, 0, stream>>>(deg, counter, NN);
  k_count<<<nb_e, 256, 0, stream>>>(dstp, deg, NE);
  k_alloc<<<nb_n, 256, 0, stream>>>(deg, dinv, offsets, cursor, counter, NN);
  k_fill<<<nb_e, 256, 0, stream>>>(srcp, dstp, dinv, cursor, adj_src, adj_nm, NE);
  k_padw1<<<48, 256, 0, stream>>>(gw[0], w1p);

  k_cnn<<<NN / 2, 256, 0, stream>>>(x, cw1, cb1, cw2, cb2, cw3, cb3, bufA);

  int gx = (NN + 63) / 64;
  // L1: H[N,96] @ W1p[96,128] -> agg(FO=128) tanh
  k_gemm<96, 128, 64><<<dim3(gx, 2), 256, 0, stream>>>(bufA, w1p, bufB, NN);
  k_agg<128, false><<<(NN + 1) / 2, 256, 0, stream>>>(bufB, offsets, deg, adj_src, adj_nm, dinv,
                                                      gb[0], bng[0], bnb[0], bnm[0], bnv[0], bufC, NN);
  // L2: [N,128]@[128,128]
  k_gemm<128, 128, 64><<<dim3(gx, 2), 256, 0, stream>>>(bufC, gw[1], bufB, NN);
  k_agg<128, false><<<(NN + 1) / 2, 256, 0, stream>>>(bufB, offsets, deg, adj_src, adj_nm, dinv,
                                                      gb[1], bng[1], bnb[1], bnm[1], bnv[1], bufA, NN);
  // L3: [N,128]@[128,64]
  k_gemm<128, 64, 64><<<dim3(gx, 1), 256, 0, stream>>>(bufA, gw[2], bufB, NN);
  k_agg<64, false><<<(NN + 3) / 4, 256, 0, stream>>>(bufB, offsets, deg, adj_src, adj_nm, dinv,
                                                     gb[2], bng[2], bnb[2], bnm[2], bnv[2], bufC, NN);
  // L4: [N,64]@[64,64]
  k_gemm<64, 64, 64><<<dim3(gx, 1), 256, 0, stream>>>(bufC, gw[3], bufB, NN);
  k_agg<64, false><<<(NN + 3) / 4, 256, 0, stream>>>(bufB, offsets, deg, adj_src, adj_nm, dinv,
                                                     gb[3], bng[3], bnb[3], bnm[3], bnv[3], bufA, NN);
  // L5: [N,64]@[64,16] -> agg + BN + softmax -> d_out
  k_gemm<64, 16, 16><<<dim3(gx, 1), 256, 0, stream>>>(bufA, gw[4], bufB, NN);
  k_agg<16, true><<<(NN + 15) / 16, 256, 0, stream>>>(bufB, offsets, deg, adj_src, adj_nm, dinv,
                                                      gb[4], bng[4], bnb[4], bnm[4], bnv[4], (float*)d_out, NN);
}

// Round 5
// 2390.585 us; speedup vs baseline: 1.2554x; 1.0672x over previous
//
#include <hip/hip_runtime.h>
#include <math.h>

namespace {

constexpr int NN = 100000;
constexpr int NE = 1600000;
constexpr float EPS = 1e-5f;

// leaky(x) == max(x, 0.01x) for all x (2 instr: v_mul + v_max)
__device__ __forceinline__ float leaky(float x) { return fmaxf(x, 0.01f * x); }
__device__ __forceinline__ float ffma(float a, float b, float c) { return __builtin_fmaf(a, b, c); }

// ---------------- preprocessing: degrees, dinv, CSR-by-dst ----------------

__global__ __launch_bounds__(256) void k_init(int* __restrict__ deg, int* __restrict__ counter, int n) {
  int i = blockIdx.x * 256 + threadIdx.x;
  if (i < n) deg[i] = 1;          // self-loop
  if (i == 0) counter[0] = 0;
}

__global__ __launch_bounds__(256) void k_count(const int* __restrict__ dst, int* __restrict__ deg, int e) {
  int i = blockIdx.x * 256 + threadIdx.x;
  if (i < e) atomicAdd(&deg[dst[i]], 1);
}

// dinv = rsqrt(deg); allocate CSR slot ranges via wave-aggregated atomic
__global__ __launch_bounds__(256) void k_alloc(const int* __restrict__ deg, float* __restrict__ dinv,
                                               int* __restrict__ offsets, int* __restrict__ cursor,
                                               int* __restrict__ counter, int n) {
  int i = blockIdx.x * 256 + threadIdx.x;
  int lane = threadIdx.x & 63;
  int c = 0;
  if (i < n) {
    int d = deg[i];
    dinv[i] = rsqrtf((float)d);
    c = d - 1;                    // real in-edges only (self-loop handled analytically)
  }
  // wave inclusive scan
  int v = c;
#pragma unroll
  for (int s = 1; s < 64; s <<= 1) {
    int t = __shfl_up(v, s, 64);
    if (lane >= s) v += t;
  }
  int total = __shfl(v, 63, 64);
  int base = 0;
  if (lane == 63) base = atomicAdd(counter, total);
  base = __shfl(base, 63, 64);
  if (i < n) {
    int off = base + v - c;       // exclusive prefix
    offsets[i] = off;
    cursor[i] = off;
  }
}

__global__ __launch_bounds__(256) void k_fill(const int* __restrict__ src, const int* __restrict__ dst,
                                              const float* __restrict__ dinv, int* __restrict__ cursor,
                                              int* __restrict__ adj_src, float* __restrict__ adj_norm, int e) {
  int i = blockIdx.x * 256 + threadIdx.x;
  if (i < e) {
    int s = src[i], d = dst[i];
    int p = atomicAdd(&cursor[d], 1);
    adj_src[p] = s;
    adj_norm[p] = dinv[s] * dinv[d];
  }
}

// zero-pad gw1 [94][128] -> [96][128]
__global__ __launch_bounds__(256) void k_padw1(const float* __restrict__ gw1, float* __restrict__ w1p) {
  int i = blockIdx.x * 256 + threadIdx.x;
  if (i < 96 * 128) w1p[i] = (i < 94 * 128) ? gw1[i] : 0.f;
}

// ---------------- CNN encoder ----------------
// per node: in [1][100][5] -> conv(10,3x3)+leaky -> conv(20,3x2)+leaky -> conv(1,3x2) -> tanh
// -> H[94] (stride 96, cols 94,95 = 0)
// block = 256 threads = 2 nodes x 128 threads. conv3 fused; LDS ~38 KB.
// Occupancy model (R1-R4 counters): waves/SIMD = floor(256/VGPR) -> need VGPR<=84 for
// 3 blocks/CU. fmaf-form conv2 peak live regs ~65, so (256,3) cap is safe (R3's failure
// was a 64-reg cap vs ~100 live).
__global__ __launch_bounds__(256, 3) void k_cnn(const float* __restrict__ x,
                                             const float* __restrict__ cw1, const float* __restrict__ cb1,
                                             const float* __restrict__ cw2, const float* __restrict__ cb2,
                                             const float* __restrict__ cw3, const float* __restrict__ cb3,
                                             float* __restrict__ H) {
  __shared__ float w1s[90];
  __shared__ float b1s[10];
  __shared__ __align__(16) float w2s[1600];   // [co*10+ci]*8 + q  (q=kh*2+kw, pad 6..7)
  __shared__ float b2s[20];
  __shared__ __align__(16) float w3s[160];    // ci*8 + q (pad 6..7)
  __shared__ float b3sv[1];
  __shared__ __align__(16) float inb[2][500];
  __shared__ float c1[2][2940];               // [10 ci][98 h][3 w]
  __shared__ float part[2][4][98];            // conv3 partial sums per cog

  int tid = threadIdx.x;
  if (tid < 90) w1s[tid] = cw1[tid];
  if (tid < 10) b1s[tid] = cb1[tid];
  for (int i = tid; i < 1200; i += 256) w2s[(i / 6) * 8 + i % 6] = cw2[i];
  if (tid < 20) b2s[tid] = cb2[tid];
  if (tid < 120) w3s[(tid / 6) * 8 + tid % 6] = cw3[tid];
  if (tid == 0) b3sv[0] = cb3[0];
  for (int i = tid; i < 2 * 4 * 98; i += 256) ((float*)part)[i] = 0.f;

  int half = tid >> 7;          // which node in block
  int nt = tid & 127;           // thread id within node
  int node = blockIdx.x * 2 + half;

  if (nt < 125) {
    const float4* xp = (const float4*)(x + (size_t)node * 500);
    ((float4*)inb[half])[nt] = xp[nt];
  }
  __syncthreads();

  {
    // conv1: positions p=(h,w) over 98x3, all 10 co per thread
    const float* in = inb[half];
    float* c1p = c1[half];
    for (int p = nt; p < 294; p += 128) {
      int h = p / 3, w = p - h * 3;
      float xv[9];
#pragma unroll
      for (int kh = 0; kh < 3; kh++)
#pragma unroll
        for (int kw = 0; kw < 3; kw++) xv[kh * 3 + kw] = in[(h + kh) * 5 + w + kw];
#pragma unroll
      for (int co = 0; co < 10; co++) {
        float a = b1s[co];
#pragma unroll
        for (int q = 0; q < 9; q++) a = ffma(xv[q], w1s[co * 9 + q], a);
        c1p[co * 294 + p] = leaky(a);
      }
    }
  }
  __syncthreads();

  // conv2: thread tile = 3h x 2w x 5co; 32 h-groups x 4 co-groups = 128 threads/node
  int hg = nt & 31, cog = nt >> 5;
  int h0 = hg * 3, co0 = cog * 5;
  float acc[3][2][5];
  {
    float* c1p = c1[half];
#pragma unroll
    for (int a = 0; a < 3; a++)
#pragma unroll
      for (int b = 0; b < 2; b++)
#pragma unroll
        for (int c = 0; c < 5; c++) acc[a][b][c] = 0.f;
#pragma unroll 1
    for (int ci = 0; ci < 10; ci++) {
      float r[5][3];
      const float* base = c1p + ci * 294 + h0 * 3;
#pragma unroll
      for (int i = 0; i < 5; i++)
#pragma unroll
        for (int j = 0; j < 3; j++) r[i][j] = base[i * 3 + j];
#pragma unroll
      for (int c = 0; c < 5; c++) {
        const float4 a4 = *(const float4*)&w2s[((co0 + c) * 10 + ci) * 8];
        const float2 a2 = *(const float2*)&w2s[((co0 + c) * 10 + ci) * 8 + 4];
#pragma unroll
        for (int hh = 0; hh < 3; hh++)
#pragma unroll
          for (int w = 0; w < 2; w++) {
            float t = acc[hh][w][c];
            t = ffma(r[hh][w],     a4.x, t);
            t = ffma(r[hh][w + 1], a4.y, t);
            t = ffma(r[hh + 1][w],     a4.z, t);
            t = ffma(r[hh + 1][w + 1], a4.w, t);
            t = ffma(r[hh + 2][w],     a2.x, t);
            t = ffma(r[hh + 2][w + 1], a2.y, t);
            acc[hh][w][c] = t;
          }
      }
    }
    // bias + leaky -> acc now holds c2 values for rows h0..h0+2, co0..co0+4
#pragma unroll
    for (int hh = 0; hh < 3; hh++)
#pragma unroll
      for (int w = 0; w < 2; w++)
#pragma unroll
        for (int c = 0; c < 5; c++)
          acc[hh][w][c] = leaky(acc[hh][w][c] + b2s[co0 + c]);
  }
  __syncthreads();   // part[] zeroing and conv2 regs complete

  // conv3 fused: H[h] = b3 + sum_{ci,kh,kw} c2[ci][h+kh][kw]*w3[ci][kh*2+kw]
  // thread contributes its acc tile to part[half][cog][h+2], phased by kh so that
  // within a phase every LDS address is written by exactly one thread of the block.
  {
    float* pp = &part[half][cog][0];
#pragma unroll
    for (int kh = 0; kh < 3; kh++) {
#pragma unroll
      for (int hh = 0; hh < 3; hh++) {
        float s = 0.f;
#pragma unroll
        for (int c = 0; c < 5; c++) {
          const float2 w2v = *(const float2*)&w3s[(co0 + c) * 8 + kh * 2];
          s = ffma(acc[hh][0][c], w2v.x, s);
          s = ffma(acc[hh][1][c], w2v.y, s);
        }
        pp[h0 + hh - kh + 2] += s;   // addresses distinct across block within this kh
      }
      __syncthreads();
    }
  }

  {
    float* Hp = H + (size_t)node * 96;
    if (nt < 94) {
      float v = part[half][0][nt + 2] + part[half][1][nt + 2]
              + part[half][2][nt + 2] + part[half][3][nt + 2] + b3sv[0];
      Hp[nt] = tanhf(v);
    } else if (nt < 96) {
      Hp[nt] = 0.f;
    }
  }
}

// ---------------- GEMM: C[M,FO-tile] = A[M,K] @ W[K,FO] ----------------
template <int K, int FO, int BN>
__global__ __launch_bounds__(256) void k_gemm(const float* __restrict__ A, const float* __restrict__ W,
                                              float* __restrict__ C, int M) {
  __shared__ float As[64][K + 1];
  __shared__ __align__(16) float Ws[K][BN];
  int tid = threadIdx.x;
  int row_base = blockIdx.x * 64;
  int col_base = blockIdx.y * BN;

  for (int idx = tid; idx < 64 * K; idx += 256) {
    int r = idx / K, k = idx - r * K;
    int row = row_base + r;
    As[r][k] = (row < M) ? A[(size_t)row * K + k] : 0.f;
  }
  for (int idx = tid; idx < K * BN; idx += 256) {
    int r = idx / BN, c = idx - r * BN;
    Ws[r][c] = W[r * FO + col_base + c];
  }
  __syncthreads();

  if constexpr (BN == 64) {
    int ty = tid >> 4, tx = tid & 15;
    float acc[4][4] = {};
#pragma unroll 4
    for (int k = 0; k < K; k++) {
      float a0 = As[ty * 4 + 0][k];
      float a1 = As[ty * 4 + 1][k];
      float a2 = As[ty * 4 + 2][k];
      float a3 = As[ty * 4 + 3][k];
      const float4 b = *(const float4*)&Ws[k][tx * 4];
      acc[0][0] = ffma(a0, b.x, acc[0][0]); acc[0][1] = ffma(a0, b.y, acc[0][1]);
      acc[0][2] = ffma(a0, b.z, acc[0][2]); acc[0][3] = ffma(a0, b.w, acc[0][3]);
      acc[1][0] = ffma(a1, b.x, acc[1][0]); acc[1][1] = ffma(a1, b.y, acc[1][1]);
      acc[1][2] = ffma(a1, b.z, acc[1][2]); acc[1][3] = ffma(a1, b.w, acc[1][3]);
      acc[2][0] = ffma(a2, b.x, acc[2][0]); acc[2][1] = ffma(a2, b.y, acc[2][1]);
      acc[2][2] = ffma(a2, b.z, acc[2][2]); acc[2][3] = ffma(a2, b.w, acc[2][3]);
      acc[3][0] = ffma(a3, b.x, acc[3][0]); acc[3][1] = ffma(a3, b.y, acc[3][1]);
      acc[3][2] = ffma(a3, b.z, acc[3][2]); acc[3][3] = ffma(a3, b.w, acc[3][3]);
    }
#pragma unroll
    for (int i = 0; i < 4; i++) {
      int row = row_base + ty * 4 + i;
      if (row < M) {
        float4 v = make_float4(acc[i][0], acc[i][1], acc[i][2], acc[i][3]);
        *(float4*)&C[(size_t)row * FO + col_base + tx * 4] = v;
      }
    }
  } else {  // BN == 16: thread = 1 row x 4 cols
    int ty = tid >> 2, tx = tid & 3;
    float acc[4] = {};
#pragma unroll 4
    for (int k = 0; k < K; k++) {
      float a = As[ty][k];
      const float4 b = *(const float4*)&Ws[k][tx * 4];
      acc[0] = ffma(a, b.x, acc[0]); acc[1] = ffma(a, b.y, acc[1]);
      acc[2] = ffma(a, b.z, acc[2]); acc[3] = ffma(a, b.w, acc[3]);
    }
    int row = row_base + ty;
    if (row < M) *(float4*)&C[(size_t)row * FO + col_base + tx * 4] = make_float4(acc[0], acc[1], acc[2], acc[3]);
  }
}

// ---------------- aggregation + bias + BN (+tanh | +softmax) ----------------
template <int FO, bool SOFT>
__global__ __launch_bounds__(256) void k_agg(const float* __restrict__ XW,
                                             const int* __restrict__ offsets, const int* __restrict__ deg,
                                             const int* __restrict__ adj_src, const float* __restrict__ adj_norm,
                                             const float* __restrict__ dinv,
                                             const float* __restrict__ gb, const float* __restrict__ bg,
                                             const float* __restrict__ bb, const float* __restrict__ bm,
                                             const float* __restrict__ bv,
                                             float* __restrict__ out, int n) {
  constexpr int NPB = 256 / FO;
  int tid = threadIdx.x;
  int li = tid / FO, col = tid % FO;
  int node = blockIdx.x * NPB + li;
  if (node >= n) return;

  float dv = dinv[node];
  float acc = XW[(size_t)node * FO + col] * dv * dv;  // self-loop
  int start = offsets[node];
  int cnt = deg[node] - 1;
  for (int e = 0; e < cnt; e++) {
    int s = adj_src[start + e];
    float nm = adj_norm[start + e];
    acc = ffma(XW[(size_t)s * FO + col], nm, acc);
  }
  float scale = bg[col] * rsqrtf(bv[col] + EPS);
  float v = ffma(acc + gb[col] - bm[col], scale, bb[col]);
  if constexpr (SOFT) {
    float mx = v;
#pragma unroll
    for (int m = 8; m; m >>= 1) mx = fmaxf(mx, __shfl_xor(mx, m, 16));
    float ex = expf(v - mx);
    float sm = ex;
#pragma unroll
    for (int m = 8; m; m >>= 1) sm += __shfl_xor(sm, m, 16);
    out[(size_t)node * FO + col] = ex / sm;
  } else {
    out[(size_t)node * FO + col] = tanhf(v);
  }
}

}  // namespace

extern "C" void kernel_launch(void* const* d_in, const int* in_sizes, int n_in,
                              void* d_out, int out_size, void* d_ws, size_t ws_size,
                              hipStream_t stream) {
  const float* x   = (const float*)d_in[0];
  const int*   ei  = (const int*)d_in[1];
  const float* cw1 = (const float*)d_in[2];
  const float* cb1 = (const float*)d_in[3];
  const float* cw2 = (const float*)d_in[4];
  const float* cb2 = (const float*)d_in[5];
  const float* cw3 = (const float*)d_in[6];
  const float* cb3 = (const float*)d_in[7];
  const float *gw[5], *gb[5], *bng[5], *bnb[5], *bnm[5], *bnv[5];
  for (int l = 0; l < 5; l++) {
    gw[l]  = (const float*)d_in[8 + 6 * l + 0];
    gb[l]  = (const float*)d_in[8 + 6 * l + 1];
    bng[l] = (const float*)d_in[8 + 6 * l + 2];
    bnb[l] = (const float*)d_in[8 + 6 * l + 3];
    bnm[l] = (const float*)d_in[8 + 6 * l + 4];
    bnv[l] = (const float*)d_in[8 + 6 * l + 5];
  }
  const int* srcp = ei;
  const int* dstp = ei + NE;

  char* w = (char*)d_ws;
  auto alloc = [&](size_t bytes) { char* p = w; w += (bytes + 255) & ~255ULL; return p; };
  int*   deg     = (int*)alloc((size_t)NN * 4);
  int*   offsets = (int*)alloc((size_t)NN * 4);
  int*   cursor  = (int*)alloc((size_t)NN * 4);
  int*   counter = (int*)alloc(256);
  float* dinv    = (float*)alloc((size_t)NN * 4);
  int*   adj_src = (int*)alloc((size_t)NE * 4);
  float* adj_nm  = (float*)alloc((size_t)NE * 4);
  float* w1p     = (float*)alloc(96 * 128 * 4);
  float* bufA    = (float*)alloc((size_t)NN * 128 * 4);
  float* bufB    = (float*)alloc((size_t)NN * 128 * 4);
  float* bufC    = (float*)alloc((size_t)NN * 128 * 4);

  int nb_n = (NN + 255) / 256;
  int nb_e = (NE + 255) / 256;
  k_init<<<nb_n, 256, 0, stream>>>(deg, counter, NN);
  k_count<<<nb_e, 256, 0, stream>>>(dstp, deg, NE);
  k_alloc<<<nb_n, 256, 0, stream>>>(deg, dinv, offsets, cursor, counter, NN);
  k_fill<<<nb_e, 256, 0, stream>>>(srcp, dstp, dinv, cursor, adj_src, adj_nm, NE);
  k_padw1<<<48, 256, 0, stream>>>(gw[0], w1p);

  k_cnn<<<NN / 2, 256, 0, stream>>>(x, cw1, cb1, cw2, cb2, cw3, cb3, bufA);

  int gx = (NN + 63) / 64;
  // L1: H[N,96] @ W1p[96,128] -> agg(FO=128) tanh
  k_gemm<96, 128, 64><<<dim3(gx, 2), 256, 0, stream>>>(bufA, w1p, bufB, NN);
  k_agg<128, false><<<(NN + 1) / 2, 256, 0, stream>>>(bufB, offsets, deg, adj_src, adj_nm, dinv,
                                                      gb[0], bng[0], bnb[0], bnm[0], bnv[0], bufC, NN);
  // L2: [N,128]@[128,128]
  k_gemm<128, 128, 64><<<dim3(gx, 2), 256, 0, stream>>>(bufC, gw[1], bufB, NN);
  k_agg<128, false><<<(NN + 1) / 2, 256, 0, stream>>>(bufB, offsets, deg, adj_src, adj_nm, dinv,
                                                      gb[1], bng[1], bnb[1], bnm[1], bnv[1], bufA, NN);
  // L3: [N,128]@[128,64]
  k_gemm<128, 64, 64><<<dim3(gx, 1), 256, 0, stream>>>(bufA, gw[2], bufB, NN);
  k_agg<64, false><<<(NN + 3) / 4, 256, 0, stream>>>(bufB, offsets, deg, adj_src, adj_nm, dinv,
                                                     gb[2], bng[2], bnb[2], bnm[2], bnv[2], bufC, NN);
  // L4: [N,64]@[64,64]
  k_gemm<64, 64, 64><<<dim3(gx, 1), 256, 0, stream>>>(bufC, gw[3], bufB, NN);
  k_agg<64, false><<<(NN + 3) / 4, 256, 0, stream>>>(bufB, offsets, deg, adj_src, adj_nm, dinv,
                                                     gb[3], bng[3], bnb[3], bnm[3], bnv[3], bufA, NN);
  // L5: [N,64]@[64,16] -> agg + BN + softmax -> d_out
  k_gemm<64, 16, 16><<<dim3(gx, 1), 256, 0, stream>>>(bufA, gw[4], bufB, NN);
  k_agg<16, true><<<(NN + 15) / 16, 256, 0, stream>>>(bufB, offsets, deg, adj_src, adj_nm, dinv,
                                                      gb[4], bng[4], bnb[4], bnm[4], bnv[4], (float*)d_out, NN);
}

// Round 6
// 1870.909 us; speedup vs baseline: 1.6041x; 1.2778x over previous
//
#include <hip/hip_runtime.h>
#include <math.h>

namespace {

constexpr int NN = 100000;
constexpr int NE = 1600000;
constexpr float EPS = 1e-5f;

// leaky(x) == max(x, 0.01x) for all x (2 instr: v_mul + v_max)
__device__ __forceinline__ float leaky(float x) { return fmaxf(x, 0.01f * x); }
__device__ __forceinline__ float ffma(float a, float b, float c) { return __builtin_fmaf(a, b, c); }

// ---------------- preprocessing: degrees, dinv, CSR-by-dst ----------------

__global__ __launch_bounds__(256) void k_init(int* __restrict__ deg, int* __restrict__ counter, int n) {
  int i = blockIdx.x * 256 + threadIdx.x;
  if (i < n) deg[i] = 1;          // self-loop
  if (i == 0) counter[0] = 0;
}

__global__ __launch_bounds__(256) void k_count(const int* __restrict__ dst, int* __restrict__ deg, int e) {
  int i = blockIdx.x * 256 + threadIdx.x;
  if (i < e) atomicAdd(&deg[dst[i]], 1);
}

// dinv = rsqrt(deg); allocate CSR slot ranges via wave-aggregated atomic
__global__ __launch_bounds__(256) void k_alloc(const int* __restrict__ deg, float* __restrict__ dinv,
                                               int* __restrict__ offsets, int* __restrict__ cursor,
                                               int* __restrict__ counter, int n) {
  int i = blockIdx.x * 256 + threadIdx.x;
  int lane = threadIdx.x & 63;
  int c = 0;
  if (i < n) {
    int d = deg[i];
    dinv[i] = rsqrtf((float)d);
    c = d - 1;                    // real in-edges only (self-loop handled analytically)
  }
  // wave inclusive scan
  int v = c;
#pragma unroll
  for (int s = 1; s < 64; s <<= 1) {
    int t = __shfl_up(v, s, 64);
    if (lane >= s) v += t;
  }
  int total = __shfl(v, 63, 64);
  int base = 0;
  if (lane == 63) base = atomicAdd(counter, total);
  base = __shfl(base, 63, 64);
  if (i < n) {
    int off = base + v - c;       // exclusive prefix
    offsets[i] = off;
    cursor[i] = off;
  }
}

__global__ __launch_bounds__(256) void k_fill(const int* __restrict__ src, const int* __restrict__ dst,
                                              const float* __restrict__ dinv, int* __restrict__ cursor,
                                              int* __restrict__ adj_src, float* __restrict__ adj_norm, int e) {
  int i = blockIdx.x * 256 + threadIdx.x;
  if (i < e) {
    int s = src[i], d = dst[i];
    int p = atomicAdd(&cursor[d], 1);
    adj_src[p] = s;
    adj_norm[p] = dinv[s] * dinv[d];
  }
}

// zero-pad gw1 [94][128] -> [96][128]
__global__ __launch_bounds__(256) void k_padw1(const float* __restrict__ gw1, float* __restrict__ w1p) {
  int i = blockIdx.x * 256 + threadIdx.x;
  if (i < 96 * 128) w1p[i] = (i < 94 * 128) ? gw1[i] : 0.f;
}

// ---------------- CNN encoder ----------------
// per node: in [1][100][5] -> conv(10,3x3)+leaky -> conv(20,3x2)+leaky -> conv(1,3x2) -> tanh
// -> H[94] (stride 96, cols 94,95 = 0)
// block = 256 threads = 2 nodes x 128 threads. conv3 fused; LDS ~38 KB x4 = 153.6K <= 160K.
// R5: compiler hit VGPR=60 voluntarily -> cap 64 via (256,4) is safe (R3's spill was
// cap 64 vs ~100 live). Spill tripwire: hbm_bytes must stay ~1.4e8.
__global__ __launch_bounds__(256, 4) void k_cnn(const float* __restrict__ x,
                                             const float* __restrict__ cw1, const float* __restrict__ cb1,
                                             const float* __restrict__ cw2, const float* __restrict__ cb2,
                                             const float* __restrict__ cw3, const float* __restrict__ cb3,
                                             float* __restrict__ H) {
  __shared__ float w1s[90];
  __shared__ float b1s[10];
  __shared__ __align__(16) float w2s[1600];   // [co*10+ci]*8 + q  (q=kh*2+kw, pad 6..7)
  __shared__ float b2s[20];
  __shared__ __align__(16) float w3s[160];    // ci*8 + q (pad 6..7)
  __shared__ float b3sv[1];
  __shared__ __align__(16) float inb[2][500];
  __shared__ float c1[2][2940];               // [10 ci][98 h][3 w]
  __shared__ float part[2][4][98];            // conv3 partial sums per cog

  int tid = threadIdx.x;
  if (tid < 90) w1s[tid] = cw1[tid];
  if (tid < 10) b1s[tid] = cb1[tid];
  for (int i = tid; i < 1200; i += 256) w2s[(i / 6) * 8 + i % 6] = cw2[i];
  if (tid < 20) b2s[tid] = cb2[tid];
  if (tid < 120) w3s[(tid / 6) * 8 + tid % 6] = cw3[tid];
  if (tid == 0) b3sv[0] = cb3[0];
  for (int i = tid; i < 2 * 4 * 98; i += 256) ((float*)part)[i] = 0.f;

  int half = tid >> 7;          // which node in block
  int nt = tid & 127;           // thread id within node
  int node = blockIdx.x * 2 + half;

  if (nt < 125) {
    const float4* xp = (const float4*)(x + (size_t)node * 500);
    ((float4*)inb[half])[nt] = xp[nt];
  }
  __syncthreads();

  {
    // conv1: one h-row per thread (h = nt, 98 rows), 3 w-outputs x 10 co.
    // Uniform single pass: no division, xv reused across the 3 w's.
    const float* in = inb[half];
    float* c1p = c1[half];
    int h = nt;
    if (h < 98) {
      float xv[3][5];
#pragma unroll
      for (int kh = 0; kh < 3; kh++)
#pragma unroll
        for (int c = 0; c < 5; c++) xv[kh][c] = in[(h + kh) * 5 + c];
      float* rowp = c1p + h * 3;
#pragma unroll
      for (int co = 0; co < 10; co++) {
        float b = b1s[co];
        float a0 = b, a1 = b, a2 = b;
#pragma unroll
        for (int kh = 0; kh < 3; kh++)
#pragma unroll
          for (int kw = 0; kw < 3; kw++) {
            float wv = w1s[co * 9 + kh * 3 + kw];
            a0 = ffma(xv[kh][kw + 0], wv, a0);
            a1 = ffma(xv[kh][kw + 1], wv, a1);
            a2 = ffma(xv[kh][kw + 2], wv, a2);
          }
        rowp[co * 294 + 0] = leaky(a0);
        rowp[co * 294 + 1] = leaky(a1);
        rowp[co * 294 + 2] = leaky(a2);
      }
    }
  }
  __syncthreads();

  // conv2: thread tile = 3h x 2w x 5co; 32 h-groups x 4 co-groups = 128 threads/node
  int hg = nt & 31, cog = nt >> 5;
  int h0 = hg * 3, co0 = cog * 5;
  float acc[3][2][5];
  {
    float* c1p = c1[half];
#pragma unroll
    for (int a = 0; a < 3; a++)
#pragma unroll
      for (int b = 0; b < 2; b++)
#pragma unroll
        for (int c = 0; c < 5; c++) acc[a][b][c] = 0.f;
#pragma unroll 1
    for (int ci = 0; ci < 10; ci++) {
      float r[5][3];
      const float* base = c1p + ci * 294 + h0 * 3;
#pragma unroll
      for (int i = 0; i < 5; i++)
#pragma unroll
        for (int j = 0; j < 3; j++) r[i][j] = base[i * 3 + j];
#pragma unroll
      for (int c = 0; c < 5; c++) {
        const float4 a4 = *(const float4*)&w2s[((co0 + c) * 10 + ci) * 8];
        const float2 a2 = *(const float2*)&w2s[((co0 + c) * 10 + ci) * 8 + 4];
#pragma unroll
        for (int hh = 0; hh < 3; hh++)
#pragma unroll
          for (int w = 0; w < 2; w++) {
            float t = acc[hh][w][c];
            t = ffma(r[hh][w],     a4.x, t);
            t = ffma(r[hh][w + 1], a4.y, t);
            t = ffma(r[hh + 1][w],     a4.z, t);
            t = ffma(r[hh + 1][w + 1], a4.w, t);
            t = ffma(r[hh + 2][w],     a2.x, t);
            t = ffma(r[hh + 2][w + 1], a2.y, t);
            acc[hh][w][c] = t;
          }
      }
    }
    // bias + leaky -> acc now holds c2 values for rows h0..h0+2, co0..co0+4
#pragma unroll
    for (int hh = 0; hh < 3; hh++)
#pragma unroll
      for (int w = 0; w < 2; w++)
#pragma unroll
        for (int c = 0; c < 5; c++)
          acc[hh][w][c] = leaky(acc[hh][w][c] + b2s[co0 + c]);
  }
  __syncthreads();   // part[] zeroing and conv2 regs complete

  // conv3 fused: H[h] = b3 + sum_{ci,kh,kw} c2[ci][h+kh][kw]*w3[ci][kh*2+kw]
  // thread contributes its acc tile to part[half][cog][h+2], phased by kh so that
  // within a phase every LDS address is written by exactly one thread of the block.
  {
    float* pp = &part[half][cog][0];
#pragma unroll
    for (int kh = 0; kh < 3; kh++) {
#pragma unroll
      for (int hh = 0; hh < 3; hh++) {
        float s = 0.f;
#pragma unroll
        for (int c = 0; c < 5; c++) {
          const float2 w2v = *(const float2*)&w3s[(co0 + c) * 8 + kh * 2];
          s = ffma(acc[hh][0][c], w2v.x, s);
          s = ffma(acc[hh][1][c], w2v.y, s);
        }
        pp[h0 + hh - kh + 2] += s;   // addresses distinct across block within this kh
      }
      __syncthreads();
    }
  }

  {
    float* Hp = H + (size_t)node * 96;
    if (nt < 94) {
      float v = part[half][0][nt + 2] + part[half][1][nt + 2]
              + part[half][2][nt + 2] + part[half][3][nt + 2] + b3sv[0];
      Hp[nt] = tanhf(v);
    } else if (nt < 96) {
      Hp[nt] = 0.f;
    }
  }
}

// ---------------- GEMM: C[M,FO-tile] = A[M,K] @ W[K,FO] ----------------
template <int K, int FO, int BN>
__global__ __launch_bounds__(256) void k_gemm(const float* __restrict__ A, const float* __restrict__ W,
                                              float* __restrict__ C, int M) {
  __shared__ float As[64][K + 1];
  __shared__ __align__(16) float Ws[K][BN];
  int tid = threadIdx.x;
  int row_base = blockIdx.x * 64;
  int col_base = blockIdx.y * BN;

  for (int idx = tid; idx < 64 * K; idx += 256) {
    int r = idx / K, k = idx - r * K;
    int row = row_base + r;
    As[r][k] = (row < M) ? A[(size_t)row * K + k] : 0.f;
  }
  for (int idx = tid; idx < K * BN; idx += 256) {
    int r = idx / BN, c = idx - r * BN;
    Ws[r][c] = W[r * FO + col_base + c];
  }
  __syncthreads();

  if constexpr (BN == 64) {
    int ty = tid >> 4, tx = tid & 15;
    float acc[4][4] = {};
#pragma unroll 4
    for (int k = 0; k < K; k++) {
      float a0 = As[ty * 4 + 0][k];
      float a1 = As[ty * 4 + 1][k];
      float a2 = As[ty * 4 + 2][k];
      float a3 = As[ty * 4 + 3][k];
      const float4 b = *(const float4*)&Ws[k][tx * 4];
      acc[0][0] = ffma(a0, b.x, acc[0][0]); acc[0][1] = ffma(a0, b.y, acc[0][1]);
      acc[0][2] = ffma(a0, b.z, acc[0][2]); acc[0][3] = ffma(a0, b.w, acc[0][3]);
      acc[1][0] = ffma(a1, b.x, acc[1][0]); acc[1][1] = ffma(a1, b.y, acc[1][1]);
      acc[1][2] = ffma(a1, b.z, acc[1][2]); acc[1][3] = ffma(a1, b.w, acc[1][3]);
      acc[2][0] = ffma(a2, b.x, acc[2][0]); acc[2][1] = ffma(a2, b.y, acc[2][1]);
      acc[2][2] = ffma(a2, b.z, acc[2][2]); acc[2][3] = ffma(a2, b.w, acc[2][3]);
      acc[3][0] = ffma(a3, b.x, acc[3][0]); acc[3][1] = ffma(a3, b.y, acc[3][1]);
      acc[3][2] = ffma(a3, b.z, acc[3][2]); acc[3][3] = ffma(a3, b.w, acc[3][3]);
    }
#pragma unroll
    for (int i = 0; i < 4; i++) {
      int row = row_base + ty * 4 + i;
      if (row < M) {
        float4 v = make_float4(acc[i][0], acc[i][1], acc[i][2], acc[i][3]);
        *(float4*)&C[(size_t)row * FO + col_base + tx * 4] = v;
      }
    }
  } else {  // BN == 16: thread = 1 row x 4 cols
    int ty = tid >> 2, tx = tid & 3;
    float acc[4] = {};
#pragma unroll 4
    for (int k = 0; k < K; k++) {
      float a = As[ty][k];
      const float4 b = *(const float4*)&Ws[k][tx * 4];
      acc[0] = ffma(a, b.x, acc[0]); acc[1] = ffma(a, b.y, acc[1]);
      acc[2] = ffma(a, b.z, acc[2]); acc[3] = ffma(a, b.w, acc[3]);
    }
    int row = row_base + ty;
    if (row < M) *(float4*)&C[(size_t)row * FO + col_base + tx * 4] = make_float4(acc[0], acc[1], acc[2], acc[3]);
  }
}

// ---------------- aggregation + bias + BN (+tanh | +softmax) ----------------
// VEC=4: thread handles 4 columns via float4 gathers -> 4x fewer VMEM/index instrs.
template <int FO, bool SOFT>
__global__ __launch_bounds__(256) void k_agg(const float* __restrict__ XW,
                                             const int* __restrict__ offsets, const int* __restrict__ deg,
                                             const int* __restrict__ adj_src, const float* __restrict__ adj_norm,
                                             const float* __restrict__ dinv,
                                             const float* __restrict__ gb, const float* __restrict__ bg,
                                             const float* __restrict__ bb, const float* __restrict__ bm,
                                             const float* __restrict__ bv,
                                             float* __restrict__ out, int n) {
  constexpr int TPN = FO / 4;          // threads per node
  constexpr int NPB = 256 / TPN;       // nodes per block
  int tid = threadIdx.x;
  int li = tid / TPN, c4 = (tid % TPN) * 4;
  int node = blockIdx.x * NPB + li;
  if (node >= n) return;

  float dv = dinv[node];
  float se = dv * dv;
  float4 acc = *(const float4*)&XW[(size_t)node * FO + c4];
  acc.x *= se; acc.y *= se; acc.z *= se; acc.w *= se;   // self-loop
  int start = offsets[node];
  int cnt = deg[node] - 1;
  for (int e = 0; e < cnt; e++) {
    int s = adj_src[start + e];
    float nm = adj_norm[start + e];
    float4 v = *(const float4*)&XW[(size_t)s * FO + c4];
    acc.x = ffma(v.x, nm, acc.x);
    acc.y = ffma(v.y, nm, acc.y);
    acc.z = ffma(v.z, nm, acc.z);
    acc.w = ffma(v.w, nm, acc.w);
  }
  const float4 g4 = *(const float4*)&bg[c4];
  const float4 v4 = *(const float4*)&bv[c4];
  const float4 gb4 = *(const float4*)&gb[c4];
  const float4 bm4 = *(const float4*)&bm[c4];
  const float4 bb4 = *(const float4*)&bb[c4];
  float4 r;
  r.x = ffma(acc.x + gb4.x - bm4.x, g4.x * rsqrtf(v4.x + EPS), bb4.x);
  r.y = ffma(acc.y + gb4.y - bm4.y, g4.y * rsqrtf(v4.y + EPS), bb4.y);
  r.z = ffma(acc.z + gb4.z - bm4.z, g4.z * rsqrtf(v4.z + EPS), bb4.z);
  r.w = ffma(acc.w + gb4.w - bm4.w, g4.w * rsqrtf(v4.w + EPS), bb4.w);
  if constexpr (SOFT) {
    // TPN lanes per node (TPN=4 for FO=16), groups are lane-aligned
    float mx = fmaxf(fmaxf(r.x, r.y), fmaxf(r.z, r.w));
#pragma unroll
    for (int m = TPN / 2; m; m >>= 1) mx = fmaxf(mx, __shfl_xor(mx, m, TPN));
    r.x = expf(r.x - mx); r.y = expf(r.y - mx);
    r.z = expf(r.z - mx); r.w = expf(r.w - mx);
    float sm = r.x + r.y + r.z + r.w;
#pragma unroll
    for (int m = TPN / 2; m; m >>= 1) sm += __shfl_xor(sm, m, TPN);
    float inv = 1.f / sm;
    r.x *= inv; r.y *= inv; r.z *= inv; r.w *= inv;
  } else {
    r.x = tanhf(r.x); r.y = tanhf(r.y); r.z = tanhf(r.z); r.w = tanhf(r.w);
  }
  *(float4*)&out[(size_t)node * FO + c4] = r;
}

}  // namespace

extern "C" void kernel_launch(void* const* d_in, const int* in_sizes, int n_in,
                              void* d_out, int out_size, void* d_ws, size_t ws_size,
                              hipStream_t stream) {
  const float* x   = (const float*)d_in[0];
  const int*   ei  = (const int*)d_in[1];
  const float* cw1 = (const float*)d_in[2];
  const float* cb1 = (const float*)d_in[3];
  const float* cw2 = (const float*)d_in[4];
  const float* cb2 = (const float*)d_in[5];
  const float* cw3 = (const float*)d_in[6];
  const float* cb3 = (const float*)d_in[7];
  const float *gw[5], *gb[5], *bng[5], *bnb[5], *bnm[5], *bnv[5];
  for (int l = 0; l < 5; l++) {
    gw[l]  = (const float*)d_in[8 + 6 * l + 0];
    gb[l]  = (const float*)d_in[8 + 6 * l + 1];
    bng[l] = (const float*)d_in[8 + 6 * l + 2];
    bnb[l] = (const float*)d_in[8 + 6 * l + 3];
    bnm[l] = (const float*)d_in[8 + 6 * l + 4];
    bnv[l] = (const float*)d_in[8 + 6 * l + 5];
  }
  const int* srcp = ei;
  const int* dstp = ei + NE;

  char* w = (char*)d_ws;
  auto alloc = [&](size_t bytes) { char* p = w; w += (bytes + 255) & ~255ULL; return p; };
  int*   deg     = (int*)alloc((size_t)NN * 4);
  int*   offsets = (int*)alloc((size_t)NN * 4);
  int*   cursor  = (int*)alloc((size_t)NN * 4);
  int*   counter = (int*)alloc(256);
  float* dinv    = (float*)alloc((size_t)NN * 4);
  int*   adj_src = (int*)alloc((size_t)NE * 4);
  float* adj_nm  = (float*)alloc((size_t)NE * 4);
  float* w1p     = (float*)alloc(96 * 128 * 4);
  float* bufA    = (float*)alloc((size_t)NN * 128 * 4);
  float* bufB    = (float*)alloc((size_t)NN * 128 * 4);
  float* bufC    = (float*)alloc((size_t)NN * 128 * 4);

  int nb_n = (NN + 255) / 256;
  int nb_e = (NE + 255) / 256;
  k_init<<<nb_n, 256, 0, stream>>>(deg, counter, NN);
  k_count<<<nb_e, 256, 0, stream>>>(dstp, deg, NE);
  k_alloc<<<nb_n, 256, 0, stream>>>(deg, dinv, offsets, cursor, counter, NN);
  k_fill<<<nb_e, 256, 0, stream>>>(srcp, dstp, dinv, cursor, adj_src, adj_nm, NE);
  k_padw1<<<48, 256, 0, stream>>>(gw[0], w1p);

  k_cnn<<<NN / 2, 256, 0, stream>>>(x, cw1, cb1, cw2, cb2, cw3, cb3, bufA);

  int gx = (NN + 63) / 64;
  // L1: H[N,96] @ W1p[96,128] -> agg(FO=128) tanh
  k_gemm<96, 128, 64><<<dim3(gx, 2), 256, 0, stream>>>(bufA, w1p, bufB, NN);
  k_agg<128, false><<<(NN + 7) / 8, 256, 0, stream>>>(bufB, offsets, deg, adj_src, adj_nm, dinv,
                                                      gb[0], bng[0], bnb[0], bnm[0], bnv[0], bufC, NN);
  // L2: [N,128]@[128,128]
  k_gemm<128, 128, 64><<<dim3(gx, 2), 256, 0, stream>>>(bufC, gw[1], bufB, NN);
  k_agg<128, false><<<(NN + 7) / 8, 256, 0, stream>>>(bufB, offsets, deg, adj_src, adj_nm, dinv,
                                                      gb[1], bng[1], bnb[1], bnm[1], bnv[1], bufA, NN);
  // L3: [N,128]@[128,64]
  k_gemm<128, 64, 64><<<dim3(gx, 1), 256, 0, stream>>>(bufA, gw[2], bufB, NN);
  k_agg<64, false><<<(NN + 15) / 16, 256, 0, stream>>>(bufB, offsets, deg, adj_src, adj_nm, dinv,
                                                       gb[2], bng[2], bnb[2], bnm[2], bnv[2], bufC, NN);
  // L4: [N,64]@[64,64]
  k_gemm<64, 64, 64><<<dim3(gx, 1), 256, 0, stream>>>(bufC, gw[3], bufB, NN);
  k_agg<64, false><<<(NN + 15) / 16, 256, 0, stream>>>(bufB, offsets, deg, adj_src, adj_nm, dinv,
                                                       gb[3], bng[3], bnb[3], bnm[3], bnv[3], bufA, NN);
  // L5: [N,64]@[64,16] -> agg + BN + softmax -> d_out
  k_gemm<64, 16, 16><<<dim3(gx, 1), 256, 0, stream>>>(bufA, gw[4], bufB, NN);
  k_agg<16, true><<<(NN + 63) / 64, 256, 0, stream>>>(bufB, offsets, deg, adj_src, adj_nm, dinv,
                                                      gb[4], bng[4], bnb[4], bnm[4], bnv[4], (float*)d_out, NN);
}

// Round 7
// 1488.819 us; speedup vs baseline: 2.0157x; 1.2566x over previous
//
#include <hip/hip_runtime.h>
#include <math.h>

namespace {

constexpr int NN = 100000;
constexpr int NE = 1600000;
constexpr float EPS = 1e-5f;

// leaky(x) == max(x, 0.01x) for all x (2 instr: v_mul + v_max)
__device__ __forceinline__ float leaky(float x) { return fmaxf(x, 0.01f * x); }
__device__ __forceinline__ float ffma(float a, float b, float c) { return __builtin_fmaf(a, b, c); }

// ---------------- preprocessing: degrees, dinv, CSR-by-dst ----------------

__global__ __launch_bounds__(256) void k_init(int* __restrict__ deg, int* __restrict__ counter, int n) {
  int i = blockIdx.x * 256 + threadIdx.x;
  if (i < n) deg[i] = 1;          // self-loop
  if (i == 0) counter[0] = 0;
}

__global__ __launch_bounds__(256) void k_count(const int* __restrict__ dst, int* __restrict__ deg, int e) {
  int i = blockIdx.x * 256 + threadIdx.x;
  if (i < e) atomicAdd(&deg[dst[i]], 1);
}

// dinv = rsqrt(deg); allocate CSR slot ranges via wave-aggregated atomic
__global__ __launch_bounds__(256) void k_alloc(const int* __restrict__ deg, float* __restrict__ dinv,
                                               int* __restrict__ offsets, int* __restrict__ cursor,
                                               int* __restrict__ counter, int n) {
  int i = blockIdx.x * 256 + threadIdx.x;
  int lane = threadIdx.x & 63;
  int c = 0;
  if (i < n) {
    int d = deg[i];
    dinv[i] = rsqrtf((float)d);
    c = d - 1;                    // real in-edges only (self-loop handled analytically)
  }
  // wave inclusive scan
  int v = c;
#pragma unroll
  for (int s = 1; s < 64; s <<= 1) {
    int t = __shfl_up(v, s, 64);
    if (lane >= s) v += t;
  }
  int total = __shfl(v, 63, 64);
  int base = 0;
  if (lane == 63) base = atomicAdd(counter, total);
  base = __shfl(base, 63, 64);
  if (i < n) {
    int off = base + v - c;       // exclusive prefix
    offsets[i] = off;
    cursor[i] = off;
  }
}

__global__ __launch_bounds__(256) void k_fill(const int* __restrict__ src, const int* __restrict__ dst,
                                              const float* __restrict__ dinv, int* __restrict__ cursor,
                                              int* __restrict__ adj_src, float* __restrict__ adj_norm, int e) {
  int i = blockIdx.x * 256 + threadIdx.x;
  if (i < e) {
    int s = src[i], d = dst[i];
    int p = atomicAdd(&cursor[d], 1);
    adj_src[p] = s;
    adj_norm[p] = dinv[s] * dinv[d];
  }
}

// zero-pad gw1 [94][128] -> [96][128]
__global__ __launch_bounds__(256) void k_padw1(const float* __restrict__ gw1, float* __restrict__ w1p) {
  int i = blockIdx.x * 256 + threadIdx.x;
  if (i < 96 * 128) w1p[i] = (i < 94 * 128) ? gw1[i] : 0.f;
}

// ---------------- CNN encoder ----------------
// per node: in [1][100][5] -> conv(10,3x3)+leaky -> conv(20,3x2)+leaky -> conv(1,3x2) -> tanh
// -> H[94] (stride 96, cols 94,95 = 0)
// R6 lesson: LDS pipe is per-CU (shared by 4 SIMDs); weight reads must NOT go through
// LDS. Layout: block = 256 = 2 nodes x 2 waves. Wave = co-group of 10 (wave-uniform
// co0 via readfirstlane -> weights/biases are SGPR scalar loads, free as FMA operands).
// Lane = hg*2+w (32 h-groups x 2 output cols). LDS only: inb + c1 + part ~ 30.7 KB.
__global__ __launch_bounds__(256, 4) void k_cnn(const float* __restrict__ x,
                                             const float* __restrict__ cw1, const float* __restrict__ cb1,
                                             const float* __restrict__ cw2, const float* __restrict__ cb2,
                                             const float* __restrict__ cw3, const float* __restrict__ cb3,
                                             float* __restrict__ H) {
  __shared__ __align__(16) float inb[2][500];
  __shared__ float c1[2][2940];               // [10 ci][98 h][3 w]
  __shared__ float part[2][2][2][98];         // [node][co-wave][w][h] conv3 partials

  int tid = threadIdx.x;
  int half = tid >> 7;          // node within block (waves 0,1 -> node0; 2,3 -> node1)
  int nt = tid & 127;           // thread id within node
  int lane = tid & 63;
  int node = blockIdx.x * 2 + half;
  int co0 = __builtin_amdgcn_readfirstlane(((tid >> 6) & 1) * 10);  // wave-uniform co-group

  for (int i = tid; i < 2 * 2 * 2 * 98; i += 256) ((float*)part)[i] = 0.f;

  if (nt < 125) {
    const float4* xp = (const float4*)(x + (size_t)node * 500);
    ((float4*)inb[half])[nt] = xp[nt];
  }
  __syncthreads();

  {
    // conv1: one h-row per thread (h = nt, 98 rows), 3 w-outputs x 10 co.
    // Weights cw1/cb1: compile-time-uniform indices -> scalar loads.
    const float* in = inb[half];
    float* c1p = c1[half];
    int h = nt;
    if (h < 98) {
      float xv[3][5];
#pragma unroll
      for (int kh = 0; kh < 3; kh++)
#pragma unroll
        for (int c = 0; c < 5; c++) xv[kh][c] = in[(h + kh) * 5 + c];
      float* rowp = c1p + h * 3;
#pragma unroll
      for (int co = 0; co < 10; co++) {
        float b = cb1[co];
        float a0 = b, a1 = b, a2 = b;
#pragma unroll
        for (int kh = 0; kh < 3; kh++)
#pragma unroll
          for (int kw = 0; kw < 3; kw++) {
            float wv = cw1[co * 9 + kh * 3 + kw];
            a0 = ffma(xv[kh][kw + 0], wv, a0);
            a1 = ffma(xv[kh][kw + 1], wv, a1);
            a2 = ffma(xv[kh][kw + 2], wv, a2);
          }
        rowp[co * 294 + 0] = leaky(a0);
        rowp[co * 294 + 1] = leaky(a1);
        rowp[co * 294 + 2] = leaky(a2);
      }
    }
  }
  __syncthreads();

  // conv2: lane = hg*2 + w. Each lane: 3 h-rows x 1 w-col x 10 co (wave's co-group).
  // Weights via SGPR (co0 uniform, c/ci unrolled/loop -> scalar index).
  int hg = lane >> 1, w = lane & 1;
  int h0 = hg * 3;
  float acc[3][10];
#pragma unroll
  for (int a = 0; a < 3; a++)
#pragma unroll
    for (int c = 0; c < 10; c++) acc[a][c] = 0.f;
  {
    const float* c1p = c1[half];
#pragma unroll 1
    for (int ci = 0; ci < 10; ci++) {
      float r[5][2];
      const float* base = c1p + ci * 294 + h0 * 3 + w;
#pragma unroll
      for (int i = 0; i < 5; i++) {
        r[i][0] = base[i * 3];
        r[i][1] = base[i * 3 + 1];
      }
#pragma unroll
      for (int c = 0; c < 10; c++) {
        const float* wp = cw2 + (co0 + c) * 60 + ci * 6;   // [co][ci][kh][kw]
        float w0 = wp[0], w1 = wp[1], w2v = wp[2], w3v = wp[3], w4 = wp[4], w5 = wp[5];
#pragma unroll
        for (int hh = 0; hh < 3; hh++) {
          float t = acc[hh][c];
          t = ffma(r[hh][0],     w0,  t);
          t = ffma(r[hh][1],     w1,  t);
          t = ffma(r[hh + 1][0], w2v, t);
          t = ffma(r[hh + 1][1], w3v, t);
          t = ffma(r[hh + 2][0], w4,  t);
          t = ffma(r[hh + 2][1], w5,  t);
          acc[hh][c] = t;
        }
      }
    }
    // bias + leaky: acc now holds c2[co0+c][h0+hh][w]
#pragma unroll
    for (int c = 0; c < 10; c++) {
      float b = cb2[co0 + c];
#pragma unroll
      for (int hh = 0; hh < 3; hh++) acc[hh][c] = leaky(acc[hh][c] + b);
    }
  }
  __syncthreads();   // part[] zeroing done (first barrier), c1 reads done before overwrite-free conv3

  // conv3 fused: H[h] = b3 + sum_{ci3,kh,kw} c2[ci3][h+kh][kw] * w3[ci3][kh*2+kw]
  // Lane contributes to part[half][cowave][w][h0+hh-kh+2]; within a kh-phase every
  // LDS address is written by exactly one thread of the block (bijective 3hg+hh).
  {
    float* pp = &part[half][co0 == 0 ? 0 : 1][w][0];
#pragma unroll
    for (int kh = 0; kh < 3; kh++) {
      float ws[10];
#pragma unroll
      for (int c = 0; c < 10; c++) {
        float wa = cw3[(co0 + c) * 6 + kh * 2 + 0];   // scalar
        float wb = cw3[(co0 + c) * 6 + kh * 2 + 1];   // scalar
        ws[c] = w ? wb : wa;                          // v_cndmask
      }
#pragma unroll
      for (int hh = 0; hh < 3; hh++) {
        float s = 0.f;
#pragma unroll
        for (int c = 0; c < 10; c++) s = ffma(acc[hh][c], ws[c], s);
        pp[h0 + hh - kh + 2] += s;
      }
      __syncthreads();
    }
  }

  {
    float* Hp = H + (size_t)node * 96;
    if (nt < 94) {
      float v = part[half][0][0][nt + 2] + part[half][0][1][nt + 2]
              + part[half][1][0][nt + 2] + part[half][1][1][nt + 2] + cb3[0];
      Hp[nt] = tanhf(v);
    } else if (nt < 96) {
      Hp[nt] = 0.f;
    }
  }
}

// ---------------- GEMM: C[M,FO-tile] = A[M,K] @ W[K,FO] ----------------
template <int K, int FO, int BN>
__global__ __launch_bounds__(256) void k_gemm(const float* __restrict__ A, const float* __restrict__ W,
                                              float* __restrict__ C, int M) {
  __shared__ float As[64][K + 1];
  __shared__ __align__(16) float Ws[K][BN];
  int tid = threadIdx.x;
  int row_base = blockIdx.x * 64;
  int col_base = blockIdx.y * BN;

  for (int idx = tid; idx < 64 * K; idx += 256) {
    int r = idx / K, k = idx - r * K;
    int row = row_base + r;
    As[r][k] = (row < M) ? A[(size_t)row * K + k] : 0.f;
  }
  for (int idx = tid; idx < K * BN; idx += 256) {
    int r = idx / BN, c = idx - r * BN;
    Ws[r][c] = W[r * FO + col_base + c];
  }
  __syncthreads();

  if constexpr (BN == 64) {
    int ty = tid >> 4, tx = tid & 15;
    float acc[4][4] = {};
#pragma unroll 4
    for (int k = 0; k < K; k++) {
      float a0 = As[ty * 4 + 0][k];
      float a1 = As[ty * 4 + 1][k];
      float a2 = As[ty * 4 + 2][k];
      float a3 = As[ty * 4 + 3][k];
      const float4 b = *(const float4*)&Ws[k][tx * 4];
      acc[0][0] = ffma(a0, b.x, acc[0][0]); acc[0][1] = ffma(a0, b.y, acc[0][1]);
      acc[0][2] = ffma(a0, b.z, acc[0][2]); acc[0][3] = ffma(a0, b.w, acc[0][3]);
      acc[1][0] = ffma(a1, b.x, acc[1][0]); acc[1][1] = ffma(a1, b.y, acc[1][1]);
      acc[1][2] = ffma(a1, b.z, acc[1][2]); acc[1][3] = ffma(a1, b.w, acc[1][3]);
      acc[2][0] = ffma(a2, b.x, acc[2][0]); acc[2][1] = ffma(a2, b.y, acc[2][1]);
      acc[2][2] = ffma(a2, b.z, acc[2][2]); acc[2][3] = ffma(a2, b.w, acc[2][3]);
      acc[3][0] = ffma(a3, b.x, acc[3][0]); acc[3][1] = ffma(a3, b.y, acc[3][1]);
      acc[3][2] = ffma(a3, b.z, acc[3][2]); acc[3][3] = ffma(a3, b.w, acc[3][3]);
    }
#pragma unroll
    for (int i = 0; i < 4; i++) {
      int row = row_base + ty * 4 + i;
      if (row < M) {
        float4 v = make_float4(acc[i][0], acc[i][1], acc[i][2], acc[i][3]);
        *(float4*)&C[(size_t)row * FO + col_base + tx * 4] = v;
      }
    }
  } else {  // BN == 16: thread = 1 row x 4 cols
    int ty = tid >> 2, tx = tid & 3;
    float acc[4] = {};
#pragma unroll 4
    for (int k = 0; k < K; k++) {
      float a = As[ty][k];
      const float4 b = *(const float4*)&Ws[k][tx * 4];
      acc[0] = ffma(a, b.x, acc[0]); acc[1] = ffma(a, b.y, acc[1]);
      acc[2] = ffma(a, b.z, acc[2]); acc[3] = ffma(a, b.w, acc[3]);
    }
    int row = row_base + ty;
    if (row < M) *(float4*)&C[(size_t)row * FO + col_base + tx * 4] = make_float4(acc[0], acc[1], acc[2], acc[3]);
  }
}

// ---------------- aggregation + bias + BN (+tanh | +softmax) ----------------
// VEC=4: thread handles 4 columns via float4 gathers -> 4x fewer VMEM/index instrs.
template <int FO, bool SOFT>
__global__ __launch_bounds__(256) void k_agg(const float* __restrict__ XW,
                                             const int* __restrict__ offsets, const int* __restrict__ deg,
                                             const int* __restrict__ adj_src, const float* __restrict__ adj_norm,
                                             const float* __restrict__ dinv,
                                             const float* __restrict__ gb, const float* __restrict__ bg,
                                             const float* __restrict__ bb, const float* __restrict__ bm,
                                             const float* __restrict__ bv,
                                             float* __restrict__ out, int n) {
  constexpr int TPN = FO / 4;          // threads per node
  constexpr int NPB = 256 / TPN;       // nodes per block
  int tid = threadIdx.x;
  int li = tid / TPN, c4 = (tid % TPN) * 4;
  int node = blockIdx.x * NPB + li;
  if (node >= n) return;

  float dv = dinv[node];
  float se = dv * dv;
  float4 acc = *(const float4*)&XW[(size_t)node * FO + c4];
  acc.x *= se; acc.y *= se; acc.z *= se; acc.w *= se;   // self-loop
  int start = offsets[node];
  int cnt = deg[node] - 1;
  for (int e = 0; e < cnt; e++) {
    int s = adj_src[start + e];
    float nm = adj_norm[start + e];
    float4 v = *(const float4*)&XW[(size_t)s * FO + c4];
    acc.x = ffma(v.x, nm, acc.x);
    acc.y = ffma(v.y, nm, acc.y);
    acc.z = ffma(v.z, nm, acc.z);
    acc.w = ffma(v.w, nm, acc.w);
  }
  const float4 g4 = *(const float4*)&bg[c4];
  const float4 v4 = *(const float4*)&bv[c4];
  const float4 gb4 = *(const float4*)&gb[c4];
  const float4 bm4 = *(const float4*)&bm[c4];
  const float4 bb4 = *(const float4*)&bb[c4];
  float4 r;
  r.x = ffma(acc.x + gb4.x - bm4.x, g4.x * rsqrtf(v4.x + EPS), bb4.x);
  r.y = ffma(acc.y + gb4.y - bm4.y, g4.y * rsqrtf(v4.y + EPS), bb4.y);
  r.z = ffma(acc.z + gb4.z - bm4.z, g4.z * rsqrtf(v4.z + EPS), bb4.z);
  r.w = ffma(acc.w + gb4.w - bm4.w, g4.w * rsqrtf(v4.w + EPS), bb4.w);
  if constexpr (SOFT) {
    // TPN lanes per node (TPN=4 for FO=16), groups are lane-aligned
    float mx = fmaxf(fmaxf(r.x, r.y), fmaxf(r.z, r.w));
#pragma unroll
    for (int m = TPN / 2; m; m >>= 1) mx = fmaxf(mx, __shfl_xor(mx, m, TPN));
    r.x = expf(r.x - mx); r.y = expf(r.y - mx);
    r.z = expf(r.z - mx); r.w = expf(r.w - mx);
    float sm = r.x + r.y + r.z + r.w;
#pragma unroll
    for (int m = TPN / 2; m; m >>= 1) sm += __shfl_xor(sm, m, TPN);
    float inv = 1.f / sm;
    r.x *= inv; r.y *= inv; r.z *= inv; r.w *= inv;
  } else {
    r.x = tanhf(r.x); r.y = tanhf(r.y); r.z = tanhf(r.z); r.w = tanhf(r.w);
  }
  *(float4*)&out[(size_t)node * FO + c4] = r;
}

}  // namespace

extern "C" void kernel_launch(void* const* d_in, const int* in_sizes, int n_in,
                              void* d_out, int out_size, void* d_ws, size_t ws_size,
                              hipStream_t stream) {
  const float* x   = (const float*)d_in[0];
  const int*   ei  = (const int*)d_in[1];
  const float* cw1 = (const float*)d_in[2];
  const float* cb1 = (const float*)d_in[3];
  const float* cw2 = (const float*)d_in[4];
  const float* cb2 = (const float*)d_in[5];
  const float* cw3 = (const float*)d_in[6];
  const float* cb3 = (const float*)d_in[7];
  const float *gw[5], *gb[5], *bng[5], *bnb[5], *bnm[5], *bnv[5];
  for (int l = 0; l < 5; l++) {
    gw[l]  = (const float*)d_in[8 + 6 * l + 0];
    gb[l]  = (const float*)d_in[8 + 6 * l + 1];
    bng[l] = (const float*)d_in[8 + 6 * l + 2];
    bnb[l] = (const float*)d_in[8 + 6 * l + 3];
    bnm[l] = (const float*)d_in[8 + 6 * l + 4];
    bnv[l] = (const float*)d_in[8 + 6 * l + 5];
  }
  const int* srcp = ei;
  const int* dstp = ei + NE;

  char* w = (char*)d_ws;
  auto alloc = [&](size_t bytes) { char* p = w; w += (bytes + 255) & ~255ULL; return p; };
  int*   deg     = (int*)alloc((size_t)NN * 4);
  int*   offsets = (int*)alloc((size_t)NN * 4);
  int*   cursor  = (int*)alloc((size_t)NN * 4);
  int*   counter = (int*)alloc(256);
  float* dinv    = (float*)alloc((size_t)NN * 4);
  int*   adj_src = (int*)alloc((size_t)NE * 4);
  float* adj_nm  = (float*)alloc((size_t)NE * 4);
  float* w1p     = (float*)alloc(96 * 128 * 4);
  float* bufA    = (float*)alloc((size_t)NN * 128 * 4);
  float* bufB    = (float*)alloc((size_t)NN * 128 * 4);
  float* bufC    = (float*)alloc((size_t)NN * 128 * 4);

  int nb_n = (NN + 255) / 256;
  int nb_e = (NE + 255) / 256;
  k_init<<<nb_n, 256, 0, stream>>>(deg, counter, NN);
  k_count<<<nb_e, 256, 0, stream>>>(dstp, deg, NE);
  k_alloc<<<nb_n, 256, 0, stream>>>(deg, dinv, offsets, cursor, counter, NN);
  k_fill<<<nb_e, 256, 0, stream>>>(srcp, dstp, dinv, cursor, adj_src, adj_nm, NE);
  k_padw1<<<48, 256, 0, stream>>>(gw[0], w1p);

  k_cnn<<<NN / 2, 256, 0, stream>>>(x, cw1, cb1, cw2, cb2, cw3, cb3, bufA);

  int gx = (NN + 63) / 64;
  // L1: H[N,96] @ W1p[96,128] -> agg(FO=128) tanh
  k_gemm<96, 128, 64><<<dim3(gx, 2), 256, 0, stream>>>(bufA, w1p, bufB, NN);
  k_agg<128, false><<<(NN + 7) / 8, 256, 0, stream>>>(bufB, offsets, deg, adj_src, adj_nm, dinv,
                                                      gb[0], bng[0], bnb[0], bnm[0], bnv[0], bufC, NN);
  // L2: [N,128]@[128,128]
  k_gemm<128, 128, 64><<<dim3(gx, 2), 256, 0, stream>>>(bufC, gw[1], bufB, NN);
  k_agg<128, false><<<(NN + 7) / 8, 256, 0, stream>>>(bufB, offsets, deg, adj_src, adj_nm, dinv,
                                                      gb[1], bng[1], bnb[1], bnm[1], bnv[1], bufA, NN);
  // L3: [N,128]@[128,64]
  k_gemm<128, 64, 64><<<dim3(gx, 1), 256, 0, stream>>>(bufA, gw[2], bufB, NN);
  k_agg<64, false><<<(NN + 15) / 16, 256, 0, stream>>>(bufB, offsets, deg, adj_src, adj_nm, dinv,
                                                       gb[2], bng[2], bnb[2], bnm[2], bnv[2], bufC, NN);
  // L4: [N,64]@[64,64]
  k_gemm<64, 64, 64><<<dim3(gx, 1), 256, 0, stream>>>(bufC, gw[3], bufB, NN);
  k_agg<64, false><<<(NN + 15) / 16, 256, 0, stream>>>(bufB, offsets, deg, adj_src, adj_nm, dinv,
                                                       gb[3], bng[3], bnb[3], bnm[3], bnv[3], bufA, NN);
  // L5: [N,64]@[64,16] -> agg + BN + softmax -> d_out
  k_gemm<64, 16, 16><<<dim3(gx, 1), 256, 0, stream>>>(bufA, gw[4], bufB, NN);
  k_agg<16, true><<<(NN + 63) / 64, 256, 0, stream>>>(bufB, offsets, deg, adj_src, adj_nm, dinv,
                                                      gb[4], bng[4], bnb[4], bnm[4], bnv[4], (float*)d_out, NN);
}

// Round 8
// 1432.515 us; speedup vs baseline: 2.0950x; 1.0393x over previous
//
#include <hip/hip_runtime.h>
#include <math.h>

namespace {

constexpr int NN = 100000;
constexpr int NE = 1600000;
constexpr float EPS = 1e-5f;

// leaky(x) == max(x, 0.01x) for all x (2 instr: v_mul + v_max)
__device__ __forceinline__ float leaky(float x) { return fmaxf(x, 0.01f * x); }
__device__ __forceinline__ float ffma(float a, float b, float c) { return __builtin_fmaf(a, b, c); }

// ---------------- preprocessing: degrees, dinv, CSR-by-dst ----------------

__global__ __launch_bounds__(256) void k_init(int* __restrict__ deg, int* __restrict__ counter, int n) {
  int i = blockIdx.x * 256 + threadIdx.x;
  if (i < n) deg[i] = 1;          // self-loop
  if (i == 0) counter[0] = 0;
}

__global__ __launch_bounds__(256) void k_count(const int* __restrict__ dst, int* __restrict__ deg, int e) {
  int i = blockIdx.x * 256 + threadIdx.x;
  if (i < e) atomicAdd(&deg[dst[i]], 1);
}

// dinv = rsqrt(deg); allocate CSR slot ranges via wave-aggregated atomic
__global__ __launch_bounds__(256) void k_alloc(const int* __restrict__ deg, float* __restrict__ dinv,
                                               int* __restrict__ offsets, int* __restrict__ cursor,
                                               int* __restrict__ counter, int n) {
  int i = blockIdx.x * 256 + threadIdx.x;
  int lane = threadIdx.x & 63;
  int c = 0;
  if (i < n) {
    int d = deg[i];
    dinv[i] = rsqrtf((float)d);
    c = d - 1;                    // real in-edges only (self-loop handled analytically)
  }
  // wave inclusive scan
  int v = c;
#pragma unroll
  for (int s = 1; s < 64; s <<= 1) {
    int t = __shfl_up(v, s, 64);
    if (lane >= s) v += t;
  }
  int total = __shfl(v, 63, 64);
  int base = 0;
  if (lane == 63) base = atomicAdd(counter, total);
  base = __shfl(base, 63, 64);
  if (i < n) {
    int off = base + v - c;       // exclusive prefix
    offsets[i] = off;
    cursor[i] = off;
  }
}

// adj entry = (src, norm) fused in one int2 -> single 8B load per edge in k_agg
__global__ __launch_bounds__(256) void k_fill(const int* __restrict__ src, const int* __restrict__ dst,
                                              const float* __restrict__ dinv, int* __restrict__ cursor,
                                              int2* __restrict__ adj, int e) {
  int i = blockIdx.x * 256 + threadIdx.x;
  if (i < e) {
    int s = src[i], d = dst[i];
    int p = atomicAdd(&cursor[d], 1);
    adj[p] = make_int2(s, __float_as_int(dinv[s] * dinv[d]));
  }
}

// zero-pad gw1 [94][128] -> [96][128]
__global__ __launch_bounds__(256) void k_padw1(const float* __restrict__ gw1, float* __restrict__ w1p) {
  int i = blockIdx.x * 256 + threadIdx.x;
  if (i < 96 * 128) w1p[i] = (i < 94 * 128) ? gw1[i] : 0.f;
}

// precompute per-layer BN scale/shift: out = acc*scale + shift
// scale = bg*rsqrt(bv+EPS); shift = (gb-bm)*scale + bb
struct BNParams {
  const float* bg[5];
  const float* bv[5];
  const float* gb[5];
  const float* bm[5];
  const float* bb[5];
};
__global__ __launch_bounds__(512) void k_bnprep(BNParams p, float* __restrict__ scale, float* __restrict__ shift) {
  int i = threadIdx.x;                    // [0, 400)
  if (i >= 400) return;
  const int ends[5] = {128, 256, 320, 384, 400};
  int l = 0;
  while (i >= ends[l]) l++;
  int c = i - (l ? ends[l - 1] : 0);
  float sc = p.bg[l][c] * rsqrtf(p.bv[l][c] + EPS);
  scale[i] = sc;
  shift[i] = ffma(p.gb[l][c] - p.bm[l][c], sc, p.bb[l][c]);
}

// ---------------- CNN encoder ----------------
// per node: in [1][100][5] -> conv(10,3x3)+leaky -> conv(20,3x2)+leaky -> conv(1,3x2) -> tanh
// -> H[94] (stride 96, cols 94,95 = 0)
// R6 lesson: LDS pipe is per-CU (shared by 4 SIMDs); weight reads must NOT go through
// LDS. Layout: block = 256 = 2 nodes x 2 waves. Wave = co-group of 10 (wave-uniform
// co0 via readfirstlane -> weights/biases are SGPR scalar loads, free as FMA operands).
// Lane = hg*2+w (32 h-groups x 2 output cols). LDS only: inb + c1 + part ~ 30.7 KB.
__global__ __launch_bounds__(256, 4) void k_cnn(const float* __restrict__ x,
                                             const float* __restrict__ cw1, const float* __restrict__ cb1,
                                             const float* __restrict__ cw2, const float* __restrict__ cb2,
                                             const float* __restrict__ cw3, const float* __restrict__ cb3,
                                             float* __restrict__ H) {
  __shared__ __align__(16) float inb[2][500];
  __shared__ float c1[2][2940];               // [10 ci][98 h][3 w]
  __shared__ float part[2][2][2][98];         // [node][co-wave][w][h] conv3 partials

  int tid = threadIdx.x;
  int half = tid >> 7;          // node within block (waves 0,1 -> node0; 2,3 -> node1)
  int nt = tid & 127;           // thread id within node
  int lane = tid & 63;
  int node = blockIdx.x * 2 + half;
  int co0 = __builtin_amdgcn_readfirstlane(((tid >> 6) & 1) * 10);  // wave-uniform co-group

  for (int i = tid; i < 2 * 2 * 2 * 98; i += 256) ((float*)part)[i] = 0.f;

  if (nt < 125) {
    const float4* xp = (const float4*)(x + (size_t)node * 500);
    ((float4*)inb[half])[nt] = xp[nt];
  }
  __syncthreads();

  {
    // conv1: one h-row per thread (h = nt, 98 rows), 3 w-outputs x 10 co.
    // Weights cw1/cb1: compile-time-uniform indices -> scalar loads.
    const float* in = inb[half];
    float* c1p = c1[half];
    int h = nt;
    if (h < 98) {
      float xv[3][5];
#pragma unroll
      for (int kh = 0; kh < 3; kh++)
#pragma unroll
        for (int c = 0; c < 5; c++) xv[kh][c] = in[(h + kh) * 5 + c];
      float* rowp = c1p + h * 3;
#pragma unroll
      for (int co = 0; co < 10; co++) {
        float b = cb1[co];
        float a0 = b, a1 = b, a2 = b;
#pragma unroll
        for (int kh = 0; kh < 3; kh++)
#pragma unroll
          for (int kw = 0; kw < 3; kw++) {
            float wv = cw1[co * 9 + kh * 3 + kw];
            a0 = ffma(xv[kh][kw + 0], wv, a0);
            a1 = ffma(xv[kh][kw + 1], wv, a1);
            a2 = ffma(xv[kh][kw + 2], wv, a2);
          }
        rowp[co * 294 + 0] = leaky(a0);
        rowp[co * 294 + 1] = leaky(a1);
        rowp[co * 294 + 2] = leaky(a2);
      }
    }
  }
  __syncthreads();

  // conv2: lane = hg*2 + w. Each lane: 3 h-rows x 1 w-col x 10 co (wave's co-group).
  // Weights via SGPR (co0 uniform, c/ci unrolled/loop -> scalar index).
  int hg = lane >> 1, w = lane & 1;
  int h0 = hg * 3;
  float acc[3][10];
#pragma unroll
  for (int a = 0; a < 3; a++)
#pragma unroll
    for (int c = 0; c < 10; c++) acc[a][c] = 0.f;
  {
    const float* c1p = c1[half];
#pragma unroll 1
    for (int ci = 0; ci < 10; ci++) {
      float r[5][2];
      const float* base = c1p + ci * 294 + h0 * 3 + w;
#pragma unroll
      for (int i = 0; i < 5; i++) {
        r[i][0] = base[i * 3];
        r[i][1] = base[i * 3 + 1];
      }
#pragma unroll
      for (int c = 0; c < 10; c++) {
        const float* wp = cw2 + (co0 + c) * 60 + ci * 6;   // [co][ci][kh][kw]
        float w0 = wp[0], w1 = wp[1], w2v = wp[2], w3v = wp[3], w4 = wp[4], w5 = wp[5];
#pragma unroll
        for (int hh = 0; hh < 3; hh++) {
          float t = acc[hh][c];
          t = ffma(r[hh][0],     w0,  t);
          t = ffma(r[hh][1],     w1,  t);
          t = ffma(r[hh + 1][0], w2v, t);
          t = ffma(r[hh + 1][1], w3v, t);
          t = ffma(r[hh + 2][0], w4,  t);
          t = ffma(r[hh + 2][1], w5,  t);
          acc[hh][c] = t;
        }
      }
    }
    // bias + leaky: acc now holds c2[co0+c][h0+hh][w]
#pragma unroll
    for (int c = 0; c < 10; c++) {
      float b = cb2[co0 + c];
#pragma unroll
      for (int hh = 0; hh < 3; hh++) acc[hh][c] = leaky(acc[hh][c] + b);
    }
  }
  __syncthreads();   // part[] zeroing done (first barrier), c1 reads done before overwrite-free conv3

  // conv3 fused: H[h] = b3 + sum_{ci3,kh,kw} c2[ci3][h+kh][kw] * w3[ci3][kh*2+kw]
  // Lane contributes to part[half][cowave][w][h0+hh-kh+2]; within a kh-phase every
  // LDS address is written by exactly one thread of the block (bijective 3hg+hh).
  {
    float* pp = &part[half][co0 == 0 ? 0 : 1][w][0];
#pragma unroll
    for (int kh = 0; kh < 3; kh++) {
      float ws[10];
#pragma unroll
      for (int c = 0; c < 10; c++) {
        float wa = cw3[(co0 + c) * 6 + kh * 2 + 0];   // scalar
        float wb = cw3[(co0 + c) * 6 + kh * 2 + 1];   // scalar
        ws[c] = w ? wb : wa;                          // v_cndmask
      }
#pragma unroll
      for (int hh = 0; hh < 3; hh++) {
        float s = 0.f;
#pragma unroll
        for (int c = 0; c < 10; c++) s = ffma(acc[hh][c], ws[c], s);
        pp[h0 + hh - kh + 2] += s;
      }
      __syncthreads();
    }
  }

  {
    float* Hp = H + (size_t)node * 96;
    if (nt < 94) {
      float v = part[half][0][0][nt + 2] + part[half][0][1][nt + 2]
              + part[half][1][0][nt + 2] + part[half][1][1][nt + 2] + cb3[0];
      Hp[nt] = tanhf(v);
    } else if (nt < 96) {
      Hp[nt] = 0.f;
    }
  }
}

// ---------------- GEMM: C[M,FO-tile] = A[M,K] @ W[K,FO] ----------------
template <int K, int FO, int BN>
__global__ __launch_bounds__(256) void k_gemm(const float* __restrict__ A, const float* __restrict__ W,
                                              float* __restrict__ C, int M) {
  __shared__ float As[64][K + 1];
  __shared__ __align__(16) float Ws[K][BN];
  int tid = threadIdx.x;
  int row_base = blockIdx.x * 64;
  int col_base = blockIdx.y * BN;

  for (int idx = tid; idx < 64 * K; idx += 256) {
    int r = idx / K, k = idx - r * K;
    int row = row_base + r;
    As[r][k] = (row < M) ? A[(size_t)row * K + k] : 0.f;
  }
  for (int idx = tid; idx < K * BN; idx += 256) {
    int r = idx / BN, c = idx - r * BN;
    Ws[r][c] = W[r * FO + col_base + c];
  }
  __syncthreads();

  if constexpr (BN == 64) {
    int ty = tid >> 4, tx = tid & 15;
    float acc[4][4] = {};
#pragma unroll 4
    for (int k = 0; k < K; k++) {
      float a0 = As[ty * 4 + 0][k];
      float a1 = As[ty * 4 + 1][k];
      float a2 = As[ty * 4 + 2][k];
      float a3 = As[ty * 4 + 3][k];
      const float4 b = *(const float4*)&Ws[k][tx * 4];
      acc[0][0] = ffma(a0, b.x, acc[0][0]); acc[0][1] = ffma(a0, b.y, acc[0][1]);
      acc[0][2] = ffma(a0, b.z, acc[0][2]); acc[0][3] = ffma(a0, b.w, acc[0][3]);
      acc[1][0] = ffma(a1, b.x, acc[1][0]); acc[1][1] = ffma(a1, b.y, acc[1][1]);
      acc[1][2] = ffma(a1, b.z, acc[1][2]); acc[1][3] = ffma(a1, b.w, acc[1][3]);
      acc[2][0] = ffma(a2, b.x, acc[2][0]); acc[2][1] = ffma(a2, b.y, acc[2][1]);
      acc[2][2] = ffma(a2, b.z, acc[2][2]); acc[2][3] = ffma(a2, b.w, acc[2][3]);
      acc[3][0] = ffma(a3, b.x, acc[3][0]); acc[3][1] = ffma(a3, b.y, acc[3][1]);
      acc[3][2] = ffma(a3, b.z, acc[3][2]); acc[3][3] = ffma(a3, b.w, acc[3][3]);
    }
#pragma unroll
    for (int i = 0; i < 4; i++) {
      int row = row_base + ty * 4 + i;
      if (row < M) {
        float4 v = make_float4(acc[i][0], acc[i][1], acc[i][2], acc[i][3]);
        *(float4*)&C[(size_t)row * FO + col_base + tx * 4] = v;
      }
    }
  } else {  // BN == 16: thread = 1 row x 4 cols
    int ty = tid >> 2, tx = tid & 3;
    float acc[4] = {};
#pragma unroll 4
    for (int k = 0; k < K; k++) {
      float a = As[ty][k];
      const float4 b = *(const float4*)&Ws[k][tx * 4];
      acc[0] = ffma(a, b.x, acc[0]); acc[1] = ffma(a, b.y, acc[1]);
      acc[2] = ffma(a, b.z, acc[2]); acc[3] = ffma(a, b.w, acc[3]);
    }
    int row = row_base + ty;
    if (row < M) *(float4*)&C[(size_t)row * FO + col_base + tx * 4] = make_float4(acc[0], acc[1], acc[2], acc[3]);
  }
}

// ---------------- aggregation + BN (+tanh | +softmax) ----------------
// 8 cols/thread (TPN = FO/8): halves node-group width vs 4-col version -> half the
// redundant adjacency loads; 1 int2 adj load per edge; edge loop unrolled x2;
// BN via precomputed scale/shift (bnofs indexes the packed [400] arrays).
template <int FO, bool SOFT>
__global__ __launch_bounds__(256) void k_agg(const float* __restrict__ XW,
                                             const int* __restrict__ offsets, const int* __restrict__ deg,
                                             const int2* __restrict__ adj,
                                             const float* __restrict__ dinv,
                                             const float* __restrict__ bnscale, const float* __restrict__ bnshift,
                                             int bnofs, float* __restrict__ out, int n) {
  constexpr int TPN = FO / 8;          // threads per node
  constexpr int NPB = 256 / TPN;       // nodes per block
  int tid = threadIdx.x;
  int li = tid / TPN, c8 = (tid % TPN) * 8;
  int node = blockIdx.x * NPB + li;
  if (node >= n) return;

  float dv = dinv[node];
  float se = dv * dv;
  const float4* selfp = (const float4*)&XW[(size_t)node * FO + c8];
  float4 aL = selfp[0], aH = selfp[1];
  aL.x *= se; aL.y *= se; aL.z *= se; aL.w *= se;
  aH.x *= se; aH.y *= se; aH.z *= se; aH.w *= se;

  const int2* ap = adj + offsets[node];
  int cnt = deg[node] - 1;
  int e = 0;
  for (; e + 1 < cnt; e += 2) {
    int2 a0 = ap[e], a1 = ap[e + 1];
    float nm0 = __int_as_float(a0.y), nm1 = __int_as_float(a1.y);
    const float4* q0 = (const float4*)&XW[(size_t)a0.x * FO + c8];
    const float4* q1 = (const float4*)&XW[(size_t)a1.x * FO + c8];
    float4 v0 = q0[0], w0 = q0[1];
    float4 v1 = q1[0], w1 = q1[1];
    aL.x = ffma(v0.x, nm0, aL.x); aL.y = ffma(v0.y, nm0, aL.y);
    aL.z = ffma(v0.z, nm0, aL.z); aL.w = ffma(v0.w, nm0, aL.w);
    aH.x = ffma(w0.x, nm0, aH.x); aH.y = ffma(w0.y, nm0, aH.y);
    aH.z = ffma(w0.z, nm0, aH.z); aH.w = ffma(w0.w, nm0, aH.w);
    aL.x = ffma(v1.x, nm1, aL.x); aL.y = ffma(v1.y, nm1, aL.y);
    aL.z = ffma(v1.z, nm1, aL.z); aL.w = ffma(v1.w, nm1, aL.w);
    aH.x = ffma(w1.x, nm1, aH.x); aH.y = ffma(w1.y, nm1, aH.y);
    aH.z = ffma(w1.z, nm1, aH.z); aH.w = ffma(w1.w, nm1, aH.w);
  }
  if (e < cnt) {
    int2 a0 = ap[e];
    float nm0 = __int_as_float(a0.y);
    const float4* q0 = (const float4*)&XW[(size_t)a0.x * FO + c8];
    float4 v0 = q0[0], w0 = q0[1];
    aL.x = ffma(v0.x, nm0, aL.x); aL.y = ffma(v0.y, nm0, aL.y);
    aL.z = ffma(v0.z, nm0, aL.z); aL.w = ffma(v0.w, nm0, aL.w);
    aH.x = ffma(w0.x, nm0, aH.x); aH.y = ffma(w0.y, nm0, aH.y);
    aH.z = ffma(w0.z, nm0, aH.z); aH.w = ffma(w0.w, nm0, aH.w);
  }

  const float4 s4L = *(const float4*)&bnscale[bnofs + c8];
  const float4 s4H = *(const float4*)&bnscale[bnofs + c8 + 4];
  const float4 h4L = *(const float4*)&bnshift[bnofs + c8];
  const float4 h4H = *(const float4*)&bnshift[bnofs + c8 + 4];
  float r[8];
  r[0] = ffma(aL.x, s4L.x, h4L.x); r[1] = ffma(aL.y, s4L.y, h4L.y);
  r[2] = ffma(aL.z, s4L.z, h4L.z); r[3] = ffma(aL.w, s4L.w, h4L.w);
  r[4] = ffma(aH.x, s4H.x, h4H.x); r[5] = ffma(aH.y, s4H.y, h4H.y);
  r[6] = ffma(aH.z, s4H.z, h4H.z); r[7] = ffma(aH.w, s4H.w, h4H.w);

  float4 oL, oH;
  if constexpr (SOFT) {
    float mx = r[0];
#pragma unroll
    for (int i = 1; i < 8; i++) mx = fmaxf(mx, r[i]);
#pragma unroll
    for (int m = TPN / 2; m; m >>= 1) mx = fmaxf(mx, __shfl_xor(mx, m, TPN));
    float sm = 0.f;
#pragma unroll
    for (int i = 0; i < 8; i++) { r[i] = expf(r[i] - mx); sm += r[i]; }
#pragma unroll
    for (int m = TPN / 2; m; m >>= 1) sm += __shfl_xor(sm, m, TPN);
    float inv = 1.f / sm;
#pragma unroll
    for (int i = 0; i < 8; i++) r[i] *= inv;
  } else {
#pragma unroll
    for (int i = 0; i < 8; i++) r[i] = tanhf(r[i]);
  }
  oL = make_float4(r[0], r[1], r[2], r[3]);
  oH = make_float4(r[4], r[5], r[6], r[7]);
  float4* op = (float4*)&out[(size_t)node * FO + c8];
  op[0] = oL;
  op[1] = oH;
}

}  // namespace

extern "C" void kernel_launch(void* const* d_in, const int* in_sizes, int n_in,
                              void* d_out, int out_size, void* d_ws, size_t ws_size,
                              hipStream_t stream) {
  const float* x   = (const float*)d_in[0];
  const int*   ei  = (const int*)d_in[1];
  const float* cw1 = (const float*)d_in[2];
  const float* cb1 = (const float*)d_in[3];
  const float* cw2 = (const float*)d_in[4];
  const float* cb2 = (const float*)d_in[5];
  const float* cw3 = (const float*)d_in[6];
  const float* cb3 = (const float*)d_in[7];
  const float *gw[5], *gb[5], *bng[5], *bnb[5], *bnm[5], *bnv[5];
  for (int l = 0; l < 5; l++) {
    gw[l]  = (const float*)d_in[8 + 6 * l + 0];
    gb[l]  = (const float*)d_in[8 + 6 * l + 1];
    bng[l] = (const float*)d_in[8 + 6 * l + 2];
    bnb[l] = (const float*)d_in[8 + 6 * l + 3];
    bnm[l] = (const float*)d_in[8 + 6 * l + 4];
    bnv[l] = (const float*)d_in[8 + 6 * l + 5];
  }
  const int* srcp = ei;
  const int* dstp = ei + NE;

  char* w = (char*)d_ws;
  auto alloc = [&](size_t bytes) { char* p = w; w += (bytes + 255) & ~255ULL; return p; };
  int*   deg     = (int*)alloc((size_t)NN * 4);
  int*   offsets = (int*)alloc((size_t)NN * 4);
  int*   cursor  = (int*)alloc((size_t)NN * 4);
  int*   counter = (int*)alloc(256);
  float* dinv    = (float*)alloc((size_t)NN * 4);
  int2*  adj     = (int2*)alloc((size_t)NE * 8);
  float* w1p     = (float*)alloc(96 * 128 * 4);
  float* bnscale = (float*)alloc(400 * 4);
  float* bnshift = (float*)alloc(400 * 4);
  float* bufA    = (float*)alloc((size_t)NN * 128 * 4);
  float* bufB    = (float*)alloc((size_t)NN * 128 * 4);
  float* bufC    = (float*)alloc((size_t)NN * 128 * 4);

  int nb_n = (NN + 255) / 256;
  int nb_e = (NE + 255) / 256;
  k_init<<<nb_n, 256, 0, stream>>>(deg, counter, NN);
  k_count<<<nb_e, 256, 0, stream>>>(dstp, deg, NE);
  k_alloc<<<nb_n, 256, 0, stream>>>(deg, dinv, offsets, cursor, counter, NN);
  k_fill<<<nb_e, 256, 0, stream>>>(srcp, dstp, dinv, cursor, adj, NE);
  k_padw1<<<48, 256, 0, stream>>>(gw[0], w1p);
  {
    BNParams bp;
    for (int l = 0; l < 5; l++) {
      bp.bg[l] = bng[l]; bp.bv[l] = bnv[l]; bp.gb[l] = gb[l];
      bp.bm[l] = bnm[l]; bp.bb[l] = bnb[l];
    }
    k_bnprep<<<1, 512, 0, stream>>>(bp, bnscale, bnshift);
  }

  k_cnn<<<NN / 2, 256, 0, stream>>>(x, cw1, cb1, cw2, cb2, cw3, cb3, bufA);

  int gx = (NN + 63) / 64;
  // L1: H[N,96] @ W1p[96,128] -> agg(FO=128) tanh
  k_gemm<96, 128, 64><<<dim3(gx, 2), 256, 0, stream>>>(bufA, w1p, bufB, NN);
  k_agg<128, false><<<(NN + 15) / 16, 256, 0, stream>>>(bufB, offsets, deg, adj, dinv,
                                                        bnscale, bnshift, 0, bufC, NN);
  // L2: [N,128]@[128,128]
  k_gemm<128, 128, 64><<<dim3(gx, 2), 256, 0, stream>>>(bufC, gw[1], bufB, NN);
  k_agg<128, false><<<(NN + 15) / 16, 256, 0, stream>>>(bufB, offsets, deg, adj, dinv,
                                                        bnscale, bnshift, 128, bufA, NN);
  // L3: [N,128]@[128,64]
  k_gemm<128, 64, 64><<<dim3(gx, 1), 256, 0, stream>>>(bufA, gw[2], bufB, NN);
  k_agg<64, false><<<(NN + 31) / 32, 256, 0, stream>>>(bufB, offsets, deg, adj, dinv,
                                                       bnscale, bnshift, 256, bufC, NN);
  // L4: [N,64]@[64,64]
  k_gemm<64, 64, 64><<<dim3(gx, 1), 256, 0, stream>>>(bufC, gw[3], bufB, NN);
  k_agg<64, false><<<(NN + 31) / 32, 256, 0, stream>>>(bufB, offsets, deg, adj, dinv,
                                                       bnscale, bnshift, 320, bufA, NN);
  // L5: [N,64]@[64,16] -> agg + BN + softmax -> d_out
  k_gemm<64, 16, 16><<<dim3(gx, 1), 256, 0, stream>>>(bufA, gw[4], bufB, NN);
  k_agg<16, true><<<(NN + 127) / 128, 256, 0, stream>>>(bufB, offsets, deg, adj, dinv,
                                                        bnscale, bnshift, 384, (float*)d_out, NN);
}

// Round 9
// 1397.662 us; speedup vs baseline: 2.1472x; 1.0249x over previous
//
#include <hip/hip_runtime.h>
#include <math.h>

namespace {

constexpr int NN = 100000;
constexpr int NE = 1600000;
constexpr float EPS = 1e-5f;

// leaky(x) == max(x, 0.01x) for all x (2 instr: v_mul + v_max)
__device__ __forceinline__ float leaky(float x) { return fmaxf(x, 0.01f * x); }
__device__ __forceinline__ float ffma(float a, float b, float c) { return __builtin_fmaf(a, b, c); }

// ---------------- preprocessing: degrees, dinv, CSR-by-dst ----------------

__global__ __launch_bounds__(256) void k_init(int* __restrict__ deg, int* __restrict__ counter, int n) {
  int i = blockIdx.x * 256 + threadIdx.x;
  if (i < n) deg[i] = 1;          // self-loop
  if (i == 0) counter[0] = 0;
}

__global__ __launch_bounds__(256) void k_count(const int* __restrict__ dst, int* __restrict__ deg, int e) {
  int i = blockIdx.x * 256 + threadIdx.x;
  if (i < e) atomicAdd(&deg[dst[i]], 1);
}

// dinv = rsqrt(deg); allocate CSR slot ranges via wave-aggregated atomic
__global__ __launch_bounds__(256) void k_alloc(const int* __restrict__ deg, float* __restrict__ dinv,
                                               int* __restrict__ offsets, int* __restrict__ cursor,
                                               int* __restrict__ counter, int n) {
  int i = blockIdx.x * 256 + threadIdx.x;
  int lane = threadIdx.x & 63;
  int c = 0;
  if (i < n) {
    int d = deg[i];
    dinv[i] = rsqrtf((float)d);
    c = d - 1;                    // real in-edges only (self-loop handled analytically)
  }
  // wave inclusive scan
  int v = c;
#pragma unroll
  for (int s = 1; s < 64; s <<= 1) {
    int t = __shfl_up(v, s, 64);
    if (lane >= s) v += t;
  }
  int total = __shfl(v, 63, 64);
  int base = 0;
  if (lane == 63) base = atomicAdd(counter, total);
  base = __shfl(base, 63, 64);
  if (i < n) {
    int off = base + v - c;       // exclusive prefix
    offsets[i] = off;
    cursor[i] = off;
  }
}

// adj entry = (src, norm) fused in one int2 -> single 8B load per edge in k_agg
__global__ __launch_bounds__(256) void k_fill(const int* __restrict__ src, const int* __restrict__ dst,
                                              const float* __restrict__ dinv, int* __restrict__ cursor,
                                              int2* __restrict__ adj, int e) {
  int i = blockIdx.x * 256 + threadIdx.x;
  if (i < e) {
    int s = src[i], d = dst[i];
    int p = atomicAdd(&cursor[d], 1);
    adj[p] = make_int2(s, __float_as_int(dinv[s] * dinv[d]));
  }
}

// zero-pad gw1 [94][128] -> [96][128]
__global__ __launch_bounds__(256) void k_padw1(const float* __restrict__ gw1, float* __restrict__ w1p) {
  int i = blockIdx.x * 256 + threadIdx.x;
  if (i < 96 * 128) w1p[i] = (i < 94 * 128) ? gw1[i] : 0.f;
}

// precompute per-layer BN scale/shift: out = acc*scale + shift
// scale = bg*rsqrt(bv+EPS); shift = (gb-bm)*scale + bb   (gb = GCN bias, folded)
struct BNParams {
  const float* bg[5];
  const float* bv[5];
  const float* gb[5];
  const float* bm[5];
  const float* bb[5];
};
__global__ __launch_bounds__(512) void k_bnprep(BNParams p, float* __restrict__ scale, float* __restrict__ shift) {
  int i = threadIdx.x;                    // [0, 400)
  if (i >= 400) return;
  const int ends[5] = {128, 256, 320, 384, 400};
  int l = 0;
  while (i >= ends[l]) l++;
  int c = i - (l ? ends[l - 1] : 0);
  float sc = p.bg[l][c] * rsqrtf(p.bv[l][c] + EPS);
  scale[i] = sc;
  shift[i] = ffma(p.gb[l][c] - p.bm[l][c], sc, p.bb[l][c]);
}

// ---------------- CNN encoder ----------------
// (unchanged from R7/R8 — 651 us, VALUBusy 93%, control kernel)
__global__ __launch_bounds__(256, 4) void k_cnn(const float* __restrict__ x,
                                             const float* __restrict__ cw1, const float* __restrict__ cb1,
                                             const float* __restrict__ cw2, const float* __restrict__ cb2,
                                             const float* __restrict__ cw3, const float* __restrict__ cb3,
                                             float* __restrict__ H) {
  __shared__ __align__(16) float inb[2][500];
  __shared__ float c1[2][2940];               // [10 ci][98 h][3 w]
  __shared__ float part[2][2][2][98];         // [node][co-wave][w][h] conv3 partials

  int tid = threadIdx.x;
  int half = tid >> 7;          // node within block (waves 0,1 -> node0; 2,3 -> node1)
  int nt = tid & 127;           // thread id within node
  int lane = tid & 63;
  int node = blockIdx.x * 2 + half;
  int co0 = __builtin_amdgcn_readfirstlane(((tid >> 6) & 1) * 10);  // wave-uniform co-group

  for (int i = tid; i < 2 * 2 * 2 * 98; i += 256) ((float*)part)[i] = 0.f;

  if (nt < 125) {
    const float4* xp = (const float4*)(x + (size_t)node * 500);
    ((float4*)inb[half])[nt] = xp[nt];
  }
  __syncthreads();

  {
    // conv1: one h-row per thread (h = nt, 98 rows), 3 w-outputs x 10 co.
    const float* in = inb[half];
    float* c1p = c1[half];
    int h = nt;
    if (h < 98) {
      float xv[3][5];
#pragma unroll
      for (int kh = 0; kh < 3; kh++)
#pragma unroll
        for (int c = 0; c < 5; c++) xv[kh][c] = in[(h + kh) * 5 + c];
      float* rowp = c1p + h * 3;
#pragma unroll
      for (int co = 0; co < 10; co++) {
        float b = cb1[co];
        float a0 = b, a1 = b, a2 = b;
#pragma unroll
        for (int kh = 0; kh < 3; kh++)
#pragma unroll
          for (int kw = 0; kw < 3; kw++) {
            float wv = cw1[co * 9 + kh * 3 + kw];
            a0 = ffma(xv[kh][kw + 0], wv, a0);
            a1 = ffma(xv[kh][kw + 1], wv, a1);
            a2 = ffma(xv[kh][kw + 2], wv, a2);
          }
        rowp[co * 294 + 0] = leaky(a0);
        rowp[co * 294 + 1] = leaky(a1);
        rowp[co * 294 + 2] = leaky(a2);
      }
    }
  }
  __syncthreads();

  // conv2: lane = hg*2 + w. Each lane: 3 h-rows x 1 w-col x 10 co (wave's co-group).
  int hg = lane >> 1, w = lane & 1;
  int h0 = hg * 3;
  float acc[3][10];
#pragma unroll
  for (int a = 0; a < 3; a++)
#pragma unroll
    for (int c = 0; c < 10; c++) acc[a][c] = 0.f;
  {
    const float* c1p = c1[half];
#pragma unroll 1
    for (int ci = 0; ci < 10; ci++) {
      float r[5][2];
      const float* base = c1p + ci * 294 + h0 * 3 + w;
#pragma unroll
      for (int i = 0; i < 5; i++) {
        r[i][0] = base[i * 3];
        r[i][1] = base[i * 3 + 1];
      }
#pragma unroll
      for (int c = 0; c < 10; c++) {
        const float* wp = cw2 + (co0 + c) * 60 + ci * 6;   // [co][ci][kh][kw]
        float w0 = wp[0], w1 = wp[1], w2v = wp[2], w3v = wp[3], w4 = wp[4], w5 = wp[5];
#pragma unroll
        for (int hh = 0; hh < 3; hh++) {
          float t = acc[hh][c];
          t = ffma(r[hh][0],     w0,  t);
          t = ffma(r[hh][1],     w1,  t);
          t = ffma(r[hh + 1][0], w2v, t);
          t = ffma(r[hh + 1][1], w3v, t);
          t = ffma(r[hh + 2][0], w4,  t);
          t = ffma(r[hh + 2][1], w5,  t);
          acc[hh][c] = t;
        }
      }
    }
#pragma unroll
    for (int c = 0; c < 10; c++) {
      float b = cb2[co0 + c];
#pragma unroll
      for (int hh = 0; hh < 3; hh++) acc[hh][c] = leaky(acc[hh][c] + b);
    }
  }
  __syncthreads();

  // conv3 fused via phased part[] accumulation
  {
    float* pp = &part[half][co0 == 0 ? 0 : 1][w][0];
#pragma unroll
    for (int kh = 0; kh < 3; kh++) {
      float ws[10];
#pragma unroll
      for (int c = 0; c < 10; c++) {
        float wa = cw3[(co0 + c) * 6 + kh * 2 + 0];   // scalar
        float wb = cw3[(co0 + c) * 6 + kh * 2 + 1];   // scalar
        ws[c] = w ? wb : wa;                          // v_cndmask
      }
#pragma unroll
      for (int hh = 0; hh < 3; hh++) {
        float s = 0.f;
#pragma unroll
        for (int c = 0; c < 10; c++) s = ffma(acc[hh][c], ws[c], s);
        pp[h0 + hh - kh + 2] += s;
      }
      __syncthreads();
    }
  }

  {
    float* Hp = H + (size_t)node * 96;
    if (nt < 94) {
      float v = part[half][0][0][nt + 2] + part[half][0][1][nt + 2]
              + part[half][1][0][nt + 2] + part[half][1][1][nt + 2] + cb3[0];
      Hp[nt] = tanhf(v);
    } else if (nt < 96) {
      Hp[nt] = 0.f;
    }
  }
}

// ---------------- GEMM: C[M,FO-tile] = A[M,K] @ W[K,FO] (+ optional BN+tanh epilogue) ----
template <int K, int FO, int BN, bool EPI = false>
__global__ __launch_bounds__(256) void k_gemm(const float* __restrict__ A, const float* __restrict__ W,
                                              float* __restrict__ C, int M,
                                              const float* __restrict__ bns = nullptr,
                                              const float* __restrict__ bnh = nullptr,
                                              int bnofs = 0) {
  __shared__ float As[64][K + 1];
  __shared__ __align__(16) float Ws[K][BN];
  int tid = threadIdx.x;
  int row_base = blockIdx.x * 64;
  int col_base = blockIdx.y * BN;

  for (int idx = tid; idx < 64 * K; idx += 256) {
    int r = idx / K, k = idx - r * K;
    int row = row_base + r;
    As[r][k] = (row < M) ? A[(size_t)row * K + k] : 0.f;
  }
  for (int idx = tid; idx < K * BN; idx += 256) {
    int r = idx / BN, c = idx - r * BN;
    Ws[r][c] = W[r * FO + col_base + c];
  }
  __syncthreads();

  if constexpr (BN == 64) {
    int ty = tid >> 4, tx = tid & 15;
    float acc[4][4] = {};
#pragma unroll 4
    for (int k = 0; k < K; k++) {
      float a0 = As[ty * 4 + 0][k];
      float a1 = As[ty * 4 + 1][k];
      float a2 = As[ty * 4 + 2][k];
      float a3 = As[ty * 4 + 3][k];
      const float4 b = *(const float4*)&Ws[k][tx * 4];
      acc[0][0] = ffma(a0, b.x, acc[0][0]); acc[0][1] = ffma(a0, b.y, acc[0][1]);
      acc[0][2] = ffma(a0, b.z, acc[0][2]); acc[0][3] = ffma(a0, b.w, acc[0][3]);
      acc[1][0] = ffma(a1, b.x, acc[1][0]); acc[1][1] = ffma(a1, b.y, acc[1][1]);
      acc[1][2] = ffma(a1, b.z, acc[1][2]); acc[1][3] = ffma(a1, b.w, acc[1][3]);
      acc[2][0] = ffma(a2, b.x, acc[2][0]); acc[2][1] = ffma(a2, b.y, acc[2][1]);
      acc[2][2] = ffma(a2, b.z, acc[2][2]); acc[2][3] = ffma(a2, b.w, acc[2][3]);
      acc[3][0] = ffma(a3, b.x, acc[3][0]); acc[3][1] = ffma(a3, b.y, acc[3][1]);
      acc[3][2] = ffma(a3, b.z, acc[3][2]); acc[3][3] = ffma(a3, b.w, acc[3][3]);
    }
    float4 s4, h4;
    if constexpr (EPI) {
      s4 = *(const float4*)&bns[bnofs + col_base + tx * 4];
      h4 = *(const float4*)&bnh[bnofs + col_base + tx * 4];
    }
#pragma unroll
    for (int i = 0; i < 4; i++) {
      int row = row_base + ty * 4 + i;
      if (row < M) {
        float4 v;
        if constexpr (EPI) {
          v.x = tanhf(ffma(acc[i][0], s4.x, h4.x));
          v.y = tanhf(ffma(acc[i][1], s4.y, h4.y));
          v.z = tanhf(ffma(acc[i][2], s4.z, h4.z));
          v.w = tanhf(ffma(acc[i][3], s4.w, h4.w));
        } else {
          v = make_float4(acc[i][0], acc[i][1], acc[i][2], acc[i][3]);
        }
        *(float4*)&C[(size_t)row * FO + col_base + tx * 4] = v;
      }
    }
  } else {  // BN == 16: thread = 1 row x 4 cols
    int ty = tid >> 2, tx = tid & 3;
    float acc[4] = {};
#pragma unroll 4
    for (int k = 0; k < K; k++) {
      float a = As[ty][k];
      const float4 b = *(const float4*)&Ws[k][tx * 4];
      acc[0] = ffma(a, b.x, acc[0]); acc[1] = ffma(a, b.y, acc[1]);
      acc[2] = ffma(a, b.z, acc[2]); acc[3] = ffma(a, b.w, acc[3]);
    }
    int row = row_base + ty;
    if (row < M) *(float4*)&C[(size_t)row * FO + col_base + tx * 4] = make_float4(acc[0], acc[1], acc[2], acc[3]);
  }
}

// ---------------- plain aggregation for L1 (FO=96): AH = A_norm @ H ----------------
// 8 lanes/node x 12 cols (3 float4). No BN/activation. Unroll x2.
__global__ __launch_bounds__(256) void k_agg96(const float* __restrict__ Hm,
                                               const int* __restrict__ offsets, const int* __restrict__ deg,
                                               const int2* __restrict__ adj,
                                               const float* __restrict__ dinv,
                                               float* __restrict__ out, int n) {
  int tid = threadIdx.x;
  int li = tid >> 3, c12 = (tid & 7) * 12;
  int node = blockIdx.x * 32 + li;
  if (node >= n) return;

  float dv = dinv[node];
  float se = dv * dv;
  const float4* sp = (const float4*)&Hm[(size_t)node * 96 + c12];
  float4 a0 = sp[0], a1 = sp[1], a2 = sp[2];
  a0.x *= se; a0.y *= se; a0.z *= se; a0.w *= se;
  a1.x *= se; a1.y *= se; a1.z *= se; a1.w *= se;
  a2.x *= se; a2.y *= se; a2.z *= se; a2.w *= se;

  const int2* ap = adj + offsets[node];
  int cnt = deg[node] - 1;
  int e = 0;
  for (; e + 1 < cnt; e += 2) {
    int2 e0 = ap[e], e1 = ap[e + 1];
    float n0 = __int_as_float(e0.y), n1 = __int_as_float(e1.y);
    const float4* q0 = (const float4*)&Hm[(size_t)e0.x * 96 + c12];
    const float4* q1 = (const float4*)&Hm[(size_t)e1.x * 96 + c12];
    float4 u0 = q0[0], u1 = q0[1], u2 = q0[2];
    float4 v0 = q1[0], v1 = q1[1], v2 = q1[2];
    a0.x = ffma(u0.x, n0, a0.x); a0.y = ffma(u0.y, n0, a0.y);
    a0.z = ffma(u0.z, n0, a0.z); a0.w = ffma(u0.w, n0, a0.w);
    a1.x = ffma(u1.x, n0, a1.x); a1.y = ffma(u1.y, n0, a1.y);
    a1.z = ffma(u1.z, n0, a1.z); a1.w = ffma(u1.w, n0, a1.w);
    a2.x = ffma(u2.x, n0, a2.x); a2.y = ffma(u2.y, n0, a2.y);
    a2.z = ffma(u2.z, n0, a2.z); a2.w = ffma(u2.w, n0, a2.w);
    a0.x = ffma(v0.x, n1, a0.x); a0.y = ffma(v0.y, n1, a0.y);
    a0.z = ffma(v0.z, n1, a0.z); a0.w = ffma(v0.w, n1, a0.w);
    a1.x = ffma(v1.x, n1, a1.x); a1.y = ffma(v1.y, n1, a1.y);
    a1.z = ffma(v1.z, n1, a1.z); a1.w = ffma(v1.w, n1, a1.w);
    a2.x = ffma(v2.x, n1, a2.x); a2.y = ffma(v2.y, n1, a2.y);
    a2.z = ffma(v2.z, n1, a2.z); a2.w = ffma(v2.w, n1, a2.w);
  }
  if (e < cnt) {
    int2 e0 = ap[e];
    float n0 = __int_as_float(e0.y);
    const float4* q0 = (const float4*)&Hm[(size_t)e0.x * 96 + c12];
    float4 u0 = q0[0], u1 = q0[1], u2 = q0[2];
    a0.x = ffma(u0.x, n0, a0.x); a0.y = ffma(u0.y, n0, a0.y);
    a0.z = ffma(u0.z, n0, a0.z); a0.w = ffma(u0.w, n0, a0.w);
    a1.x = ffma(u1.x, n0, a1.x); a1.y = ffma(u1.y, n0, a1.y);
    a1.z = ffma(u1.z, n0, a1.z); a1.w = ffma(u1.w, n0, a1.w);
    a2.x = ffma(u2.x, n0, a2.x); a2.y = ffma(u2.y, n0, a2.y);
    a2.z = ffma(u2.z, n0, a2.z); a2.w = ffma(u2.w, n0, a2.w);
  }
  float4* op = (float4*)&out[(size_t)node * 96 + c12];
  op[0] = a0; op[1] = a1; op[2] = a2;
}

// ---------------- aggregation + BN (+tanh | +softmax) ----------------
// 8 cols/thread; 1 int2 adj load per edge; edge loop unrolled x4 (8 gathers in flight);
// BN via precomputed scale/shift.
template <int FO, bool SOFT>
__global__ __launch_bounds__(256) void k_agg(const float* __restrict__ XW,
                                             const int* __restrict__ offsets, const int* __restrict__ deg,
                                             const int2* __restrict__ adj,
                                             const float* __restrict__ dinv,
                                             const float* __restrict__ bnscale, const float* __restrict__ bnshift,
                                             int bnofs, float* __restrict__ out, int n) {
  constexpr int TPN = FO / 8;          // threads per node
  constexpr int NPB = 256 / TPN;       // nodes per block
  int tid = threadIdx.x;
  int li = tid / TPN, c8 = (tid % TPN) * 8;
  int node = blockIdx.x * NPB + li;
  if (node >= n) return;

  float dv = dinv[node];
  float se = dv * dv;
  const float4* selfp = (const float4*)&XW[(size_t)node * FO + c8];
  float4 aL = selfp[0], aH = selfp[1];
  aL.x *= se; aL.y *= se; aL.z *= se; aL.w *= se;
  aH.x *= se; aH.y *= se; aH.z *= se; aH.w *= se;

  const int2* ap = adj + offsets[node];
  int cnt = deg[node] - 1;
  int e = 0;
#define EDGE_STEP(AA)                                                        \
  {                                                                          \
    float nm = __int_as_float((AA).y);                                       \
    const float4* q = (const float4*)&XW[(size_t)(AA).x * FO + c8];          \
    float4 v = q[0], w = q[1];                                               \
    aL.x = ffma(v.x, nm, aL.x); aL.y = ffma(v.y, nm, aL.y);                  \
    aL.z = ffma(v.z, nm, aL.z); aL.w = ffma(v.w, nm, aL.w);                  \
    aH.x = ffma(w.x, nm, aH.x); aH.y = ffma(w.y, nm, aH.y);                  \
    aH.z = ffma(w.z, nm, aH.z); aH.w = ffma(w.w, nm, aH.w);                  \
  }
  for (; e + 3 < cnt; e += 4) {
    int2 a0 = ap[e], a1 = ap[e + 1], a2 = ap[e + 2], a3 = ap[e + 3];
    EDGE_STEP(a0); EDGE_STEP(a1); EDGE_STEP(a2); EDGE_STEP(a3);
  }
  for (; e < cnt; e++) {
    int2 a0 = ap[e];
    EDGE_STEP(a0);
  }
#undef EDGE_STEP

  const float4 s4L = *(const float4*)&bnscale[bnofs + c8];
  const float4 s4H = *(const float4*)&bnscale[bnofs + c8 + 4];
  const float4 h4L = *(const float4*)&bnshift[bnofs + c8];
  const float4 h4H = *(const float4*)&bnshift[bnofs + c8 + 4];
  float r[8];
  r[0] = ffma(aL.x, s4L.x, h4L.x); r[1] = ffma(aL.y, s4L.y, h4L.y);
  r[2] = ffma(aL.z, s4L.z, h4L.z); r[3] = ffma(aL.w, s4L.w, h4L.w);
  r[4] = ffma(aH.x, s4H.x, h4H.x); r[5] = ffma(aH.y, s4H.y, h4H.y);
  r[6] = ffma(aH.z, s4H.z, h4H.z); r[7] = ffma(aH.w, s4H.w, h4H.w);

  float4 oL, oH;
  if constexpr (SOFT) {
    float mx = r[0];
#pragma unroll
    for (int i = 1; i < 8; i++) mx = fmaxf(mx, r[i]);
#pragma unroll
    for (int m = TPN / 2; m; m >>= 1) mx = fmaxf(mx, __shfl_xor(mx, m, TPN));
    float sm = 0.f;
#pragma unroll
    for (int i = 0; i < 8; i++) { r[i] = expf(r[i] - mx); sm += r[i]; }
#pragma unroll
    for (int m = TPN / 2; m; m >>= 1) sm += __shfl_xor(sm, m, TPN);
    float inv = 1.f / sm;
#pragma unroll
    for (int i = 0; i < 8; i++) r[i] *= inv;
  } else {
#pragma unroll
    for (int i = 0; i < 8; i++) r[i] = tanhf(r[i]);
  }
  oL = make_float4(r[0], r[1], r[2], r[3]);
  oH = make_float4(r[4], r[5], r[6], r[7]);
  float4* op = (float4*)&out[(size_t)node * FO + c8];
  op[0] = oL;
  op[1] = oH;
}

}  // namespace

extern "C" void kernel_launch(void* const* d_in, const int* in_sizes, int n_in,
                              void* d_out, int out_size, void* d_ws, size_t ws_size,
                              hipStream_t stream) {
  const float* x   = (const float*)d_in[0];
  const int*   ei  = (const int*)d_in[1];
  const float* cw1 = (const float*)d_in[2];
  const float* cb1 = (const float*)d_in[3];
  const float* cw2 = (const float*)d_in[4];
  const float* cb2 = (const float*)d_in[5];
  const float* cw3 = (const float*)d_in[6];
  const float* cb3 = (const float*)d_in[7];
  const float *gw[5], *gb[5], *bng[5], *bnb[5], *bnm[5], *bnv[5];
  for (int l = 0; l < 5; l++) {
    gw[l]  = (const float*)d_in[8 + 6 * l + 0];
    gb[l]  = (const float*)d_in[8 + 6 * l + 1];
    bng[l] = (const float*)d_in[8 + 6 * l + 2];
    bnb[l] = (const float*)d_in[8 + 6 * l + 3];
    bnm[l] = (const float*)d_in[8 + 6 * l + 4];
    bnv[l] = (const float*)d_in[8 + 6 * l + 5];
  }
  const int* srcp = ei;
  const int* dstp = ei + NE;

  char* w = (char*)d_ws;
  auto alloc = [&](size_t bytes) { char* p = w; w += (bytes + 255) & ~255ULL; return p; };
  int*   deg     = (int*)alloc((size_t)NN * 4);
  int*   offsets = (int*)alloc((size_t)NN * 4);
  int*   cursor  = (int*)alloc((size_t)NN * 4);
  int*   counter = (int*)alloc(256);
  float* dinv    = (float*)alloc((size_t)NN * 4);
  int2*  adj     = (int2*)alloc((size_t)NE * 8);
  float* w1p     = (float*)alloc(96 * 128 * 4);
  float* bnscale = (float*)alloc(400 * 4);
  float* bnshift = (float*)alloc(400 * 4);
  float* bufA    = (float*)alloc((size_t)NN * 128 * 4);
  float* bufB    = (float*)alloc((size_t)NN * 128 * 4);
  float* bufC    = (float*)alloc((size_t)NN * 128 * 4);

  int nb_n = (NN + 255) / 256;
  int nb_e = (NE + 255) / 256;
  k_init<<<nb_n, 256, 0, stream>>>(deg, counter, NN);
  k_count<<<nb_e, 256, 0, stream>>>(dstp, deg, NE);
  k_alloc<<<nb_n, 256, 0, stream>>>(deg, dinv, offsets, cursor, counter, NN);
  k_fill<<<nb_e, 256, 0, stream>>>(srcp, dstp, dinv, cursor, adj, NE);
  k_padw1<<<48, 256, 0, stream>>>(gw[0], w1p);
  {
    BNParams bp;
    for (int l = 0; l < 5; l++) {
      bp.bg[l] = bng[l]; bp.bv[l] = bnv[l]; bp.gb[l] = gb[l];
      bp.bm[l] = bnm[l]; bp.bb[l] = bnb[l];
    }
    k_bnprep<<<1, 512, 0, stream>>>(bp, bnscale, bnshift);
  }

  k_cnn<<<NN / 2, 256, 0, stream>>>(x, cw1, cb1, cw2, cb2, cw3, cb3, bufA);

  int gx = (NN + 63) / 64;
  // L1 (agg-first: fi=96 < fo=128): AH = A@H (96 cols), then GEMM + fused BN+tanh
  k_agg96<<<(NN + 31) / 32, 256, 0, stream>>>(bufA, offsets, deg, adj, dinv, bufB, NN);
  k_gemm<96, 128, 64, true><<<dim3(gx, 2), 256, 0, stream>>>(bufB, w1p, bufC, NN, bnscale, bnshift, 0);
  // L2: [N,128]@[128,128] then agg
  k_gemm<128, 128, 64><<<dim3(gx, 2), 256, 0, stream>>>(bufC, gw[1], bufB, NN);
  k_agg<128, false><<<(NN + 15) / 16, 256, 0, stream>>>(bufB, offsets, deg, adj, dinv,
                                                        bnscale, bnshift, 128, bufA, NN);
  // L3: [N,128]@[128,64] then agg
  k_gemm<128, 64, 64><<<dim3(gx, 1), 256, 0, stream>>>(bufA, gw[2], bufB, NN);
  k_agg<64, false><<<(NN + 31) / 32, 256, 0, stream>>>(bufB, offsets, deg, adj, dinv,
                                                       bnscale, bnshift, 256, bufC, NN);
  // L4: [N,64]@[64,64] then agg
  k_gemm<64, 64, 64><<<dim3(gx, 1), 256, 0, stream>>>(bufC, gw[3], bufB, NN);
  k_agg<64, false><<<(NN + 31) / 32, 256, 0, stream>>>(bufB, offsets, deg, adj, dinv,
                                                       bnscale, bnshift, 320, bufA, NN);
  // L5: [N,64]@[64,16] then agg + BN + softmax -> d_out
  k_gemm<64, 16, 16><<<dim3(gx, 1), 256, 0, stream>>>(bufA, gw[4], bufB, NN);
  k_agg<16, true><<<(NN + 127) / 128, 256, 0, stream>>>(bufB, offsets, deg, adj, dinv,
                                                        bnscale, bnshift, 384, (float*)d_out, NN);
}